// Round 6
// baseline (234.465 us; speedup 1.0000x reference)
//
#include <hip/hip_runtime.h>
#include <hip/hip_bf16.h>
#include <math.h>

#define BB 8192
#define XD 784
#define ZD 10
#define KK 2000
#define HH 300

typedef short short8 __attribute__((ext_vector_type(8)));
typedef float f32x4 __attribute__((ext_vector_type(4)));

__device__ __forceinline__ float sp_(float x) {
    return fmaxf(x, 0.f) + __logf(1.f + __expf(-fabsf(x)));
}
__device__ __forceinline__ float elu_(float x) { return x > 0.f ? x : __expf(x) - 1.f; }
__device__ __forceinline__ unsigned short bf16_(float v) {
    __hip_bfloat16 h = __float2bfloat16(v);
    return __builtin_bit_cast(unsigned short, h);
}
__device__ __forceinline__ float b2f_(unsigned short u) {
    return __builtin_bit_cast(float, (unsigned int)u << 16);
}
__device__ __forceinline__ void gl16(const unsigned short* g, unsigned short* l) {
    __builtin_amdgcn_global_load_lds(
        (const __attribute__((address_space(1))) unsigned int*)g,
        (__attribute__((address_space(3))) unsigned int*)l, 16, 0, 0);
}
template<int N> __device__ __forceinline__ void vwait() {
    if constexpr (N == 0)  asm volatile("s_waitcnt vmcnt(0)" ::: "memory");
    if constexpr (N == 4)  asm volatile("s_waitcnt vmcnt(4)" ::: "memory");
    if constexpr (N == 5)  asm volatile("s_waitcnt vmcnt(5)" ::: "memory");
    if constexpr (N == 8)  asm volatile("s_waitcnt vmcnt(8)" ::: "memory");
    if constexpr (N == 10) asm volatile("s_waitcnt vmcnt(10)" ::: "memory");
}
// fragment-major write of element (row, k) into a 32-row activation buffer
// with KS = KP/32 k-slices: addr = ((mi*KS + k/32)*64 + (row&15) + ((k>>3)&3)*16)*8 + k&7
__device__ __forceinline__ void fbw(unsigned short* fb, int row, int k, unsigned short v) {
    fb[(((row >> 4) * 2 + (k >> 5)) * 64 + (row & 15) + (((k >> 3) & 3) << 4)) * 8 + (k & 7)] = v;
}

// ---------------------------------------------------------------------------
// One fused layer: C[32 rows][NI*128 cols] = A[32][KP] @ Wt[cols][KP]^T (+epi)
// 4 waves, each 32x32 tile (2x2 frags 16x16x32), n-tile 128 cols, k-step 64.
// B (and A for AGLOB) staged via global_load_lds, 3-deep ring, counted vmcnt
// (SCNT gl16/thread per stage: waits 2*SCNT / SCNT / 0). Raw s_barrier pair
// per step (r5-validated choreography). A resident in LDS for AGLOB=false.
// LMODE 0: bf16 elu -> actout (store c<320, zero for c>=300)
// LMODE 1: fp32 c3L[row*24+c], c<20
// LMODE 2: per-row sum(x*logit - softplus(logit)), c<784 -> redL[row][wave]
// LMODE 3: per-row online logsumexp (bias=c_k from LDS) -> redM/redS
// ---------------------------------------------------------------------------
template<int LMODE, bool AGLOB, int SCNT>
__device__ __forceinline__ void layer(
    const int tid, const unsigned short* __restrict__ Ag,
    const unsigned short* __restrict__ actin,
    const unsigned short* __restrict__ Wt, const int KP, const int KI, const int NI,
    const float* __restrict__ bL, unsigned short* __restrict__ actout,
    float* __restrict__ c3L, float* __restrict__ redL,
    float* __restrict__ redM, float* __restrict__ redS,
    unsigned short* __restrict__ astg, unsigned short* __restrict__ bstg)
{
    const int w = tid >> 6, l = tid & 63;
    const int cl = l & 15, g4 = (l >> 4) << 2;
    const int KS = KP >> 5;
    const int NQ = NI * KI;

    f32x4 acc[2][2];
    float rA[2][4], rB[2][4];
    #pragma unroll
    for (int i = 0; i < 2; ++i) {
        #pragma unroll
        for (int j = 0; j < 2; ++j) acc[i][j] = (f32x4){0.f, 0.f, 0.f, 0.f};
        #pragma unroll
        for (int r = 0; r < 4; ++r) { rA[i][r] = (LMODE == 3) ? -1e30f : 0.f; rB[i][r] = 0.f; }
    }

    auto stage = [&](int ni, int ki, int buf) {
        const int n0 = ni * 128, k0 = ki * 64;
        #pragma unroll
        for (int r = 0; r < 4; ++r) {
            const int c0 = r * 256 + w * 64;           // wave-uniform chunk base
            const int nc = c0 >> 7, s = (c0 >> 6) & 1; // uniform per gl16
            const unsigned short* src =
                Wt + (size_t)(n0 + nc * 16 + cl) * KP + k0 + s * 32 + ((l >> 4) << 3);
            gl16(src, bstg + buf * 8192 + c0 * 8);
        }
        if constexpr (AGLOB) {
            const int mi = w >> 1, s = w & 1;          // uniform
            const unsigned short* src =
                Ag + (size_t)(mi * 16 + cl) * 832 + k0 + s * 32 + ((l >> 4) << 3);
            gl16(src, astg + buf * 2048 + w * 512);
        }
    };
    auto adv = [&](int& ni, int& ki) { if (++ki == KI) { ki = 0; ++ni; } };

    int sni = 0, ski = 0;
    stage(sni, ski, 0); adv(sni, ski);
    stage(sni, ski, 1); adv(sni, ski);
    int cni = 0, cki = 0, cur = 0, pf = 2;

    for (int q = 0; q < NQ; ++q) {
        if (q + 2 < NQ) { stage(sni, ski, pf); adv(sni, ski); }
        const int rem = NQ - 1 - q;
        if (rem >= 2)      vwait<2 * SCNT>();
        else if (rem == 1) vwait<SCNT>();
        else               vwait<0>();
        __builtin_amdgcn_s_barrier();
        __builtin_amdgcn_sched_barrier(0);

        short8 a[2][2], b[2][2];
        #pragma unroll
        for (int mi = 0; mi < 2; ++mi)
            #pragma unroll
            for (int s = 0; s < 2; ++s) {
                if constexpr (AGLOB)
                    a[mi][s] = *reinterpret_cast<const short8*>(
                        astg + (size_t)cur * 2048 + ((mi * 2 + s) * 64 + l) * 8);
                else
                    a[mi][s] = *reinterpret_cast<const short8*>(
                        actin + ((mi * KS + (cki * 2 + s)) * 64 + l) * 8);
            }
        #pragma unroll
        for (int nj = 0; nj < 2; ++nj)
            #pragma unroll
            for (int s = 0; s < 2; ++s)
                b[nj][s] = *reinterpret_cast<const short8*>(
                    bstg + (size_t)cur * 8192 + (((w * 2 + nj) * 2 + s) * 64 + l) * 8);
        #pragma unroll
        for (int mi = 0; mi < 2; ++mi)
            #pragma unroll
            for (int nj = 0; nj < 2; ++nj) {
                acc[mi][nj] = __builtin_amdgcn_mfma_f32_16x16x32_bf16(a[mi][0], b[nj][0], acc[mi][nj], 0, 0, 0);
                acc[mi][nj] = __builtin_amdgcn_mfma_f32_16x16x32_bf16(a[mi][1], b[nj][1], acc[mi][nj], 0, 0, 0);
            }
        asm volatile("s_waitcnt lgkmcnt(0)" ::: "memory");
        __builtin_amdgcn_sched_barrier(0);
        __builtin_amdgcn_s_barrier();
        __builtin_amdgcn_sched_barrier(0);

        if (cki == KI - 1) {
            const int n0 = cni * 128;
            if (LMODE == 0) {
                #pragma unroll
                for (int mi = 0; mi < 2; ++mi)
                    #pragma unroll
                    for (int nj = 0; nj < 2; ++nj) {
                        const int c = n0 + w * 32 + nj * 16 + cl;
                        const float bb = (c < HH) ? bL[c] : 0.f;
                        #pragma unroll
                        for (int rr = 0; rr < 4; ++rr) {
                            float o = (c < HH) ? elu_(acc[mi][nj][rr] + bb) : 0.f;
                            if (c < 320)
                                actout[((mi * 10 + (c >> 5)) * 64 + (g4 + rr) + (((c >> 3) & 3) << 4)) * 8 + (c & 7)] = bf16_(o);
                        }
                    }
            } else if (LMODE == 1) {
                #pragma unroll
                for (int mi = 0; mi < 2; ++mi)
                    #pragma unroll
                    for (int nj = 0; nj < 2; ++nj) {
                        const int c = w * 32 + nj * 16 + cl;
                        if (c < 20) {
                            #pragma unroll
                            for (int rr = 0; rr < 4; ++rr)
                                c3L[(mi * 16 + g4 + rr) * 24 + c] = acc[mi][nj][rr] + bL[c];
                        }
                    }
            } else if (LMODE == 2) {
                #pragma unroll
                for (int mi = 0; mi < 2; ++mi)
                    #pragma unroll
                    for (int rr = 0; rr < 4; ++rr) {
                        const int row = mi * 16 + g4 + rr;
                        float s2 = 0.f;
                        #pragma unroll
                        for (int nj = 0; nj < 2; ++nj) {
                            const int c = n0 + w * 32 + nj * 16 + cl;
                            if (c < XD) {
                                float lv = acc[mi][nj][rr] + bL[c];
                                float xv = b2f_(Ag[(size_t)row * 832 + c]);
                                s2 += xv * lv - sp_(lv);
                            }
                        }
                        s2 += __shfl_xor(s2, 1); s2 += __shfl_xor(s2, 2);
                        s2 += __shfl_xor(s2, 4); s2 += __shfl_xor(s2, 8);
                        rA[mi][rr] += s2;
                    }
            } else {
                const float b0 = bL[n0 + w * 32 + cl];
                const float b1 = bL[n0 + w * 32 + 16 + cl];
                #pragma unroll
                for (int mi = 0; mi < 2; ++mi)
                    #pragma unroll
                    for (int rr = 0; rr < 4; ++rr) {
                        float v0 = acc[mi][0][rr] + b0;
                        float v1 = acc[mi][1][rr] + b1;
                        float mx = fmaxf(v0, v1);
                        mx = fmaxf(mx, __shfl_xor(mx, 1)); mx = fmaxf(mx, __shfl_xor(mx, 2));
                        mx = fmaxf(mx, __shfl_xor(mx, 4)); mx = fmaxf(mx, __shfl_xor(mx, 8));
                        float s = __expf(v0 - mx) + __expf(v1 - mx);
                        s += __shfl_xor(s, 1); s += __shfl_xor(s, 2);
                        s += __shfl_xor(s, 4); s += __shfl_xor(s, 8);
                        if (mx > rA[mi][rr]) { rB[mi][rr] = rB[mi][rr] * __expf(rA[mi][rr] - mx) + s; rA[mi][rr] = mx; }
                        else                 { rB[mi][rr] += s * __expf(mx - rA[mi][rr]); }
                    }
            }
            #pragma unroll
            for (int i = 0; i < 2; ++i)
                #pragma unroll
                for (int j = 0; j < 2; ++j) acc[i][j] = (f32x4){0.f, 0.f, 0.f, 0.f};
        }
        adv(cni, cki);
        cur = (cur + 1 < 3) ? cur + 1 : 0;
        pf  = (pf  + 1 < 3) ? pf  + 1 : 0;
    }
    if (LMODE == 2 && cl == 0) {
        #pragma unroll
        for (int mi = 0; mi < 2; ++mi)
            #pragma unroll
            for (int rr = 0; rr < 4; ++rr)
                redL[(mi * 16 + g4 + rr) * 4 + w] = rA[mi][rr];
    }
    if (LMODE == 3 && cl == 0) {
        #pragma unroll
        for (int mi = 0; mi < 2; ++mi)
            #pragma unroll
            for (int rr = 0; rr < 4; ++rr) {
                redM[(mi * 16 + g4 + rr) * 4 + w] = rA[mi][rr];
                redS[(mi * 16 + g4 + rr) * 4 + w] = rB[mi][rr];
            }
    }
}

__global__ __launch_bounds__(256)
void fused_k(const unsigned short* __restrict__ xb,
             const unsigned short* __restrict__ w1t, const float* __restrict__ eb1,
             const unsigned short* __restrict__ w2t, const float* __restrict__ eb2,
             const unsigned short* __restrict__ w3t, const float* __restrict__ eb3,
             const unsigned short* __restrict__ d1t, const float* __restrict__ db1,
             const unsigned short* __restrict__ d2t, const float* __restrict__ db2,
             const unsigned short* __restrict__ d3t, const float* __restrict__ db3,
             const unsigned short* __restrict__ G,  const float* __restrict__ cbias,
             const float* __restrict__ eps, float* __restrict__ part)
{
    __shared__ __align__(16) unsigned short actP[10240], actQ[10240];
    __shared__ __align__(16) unsigned short bstg[24576], astg[6144];
    __shared__ __align__(16) unsigned short fbL[2048];
    __shared__ float biasL[896];
    __shared__ float cbL[2048];
    __shared__ float c3L[768];
    __shared__ float lqzL[32];
    __shared__ float redM[128], redS[128], redL[128];

    const int tid = threadIdx.x;
    const int m0 = blockIdx.x * 32;
    const unsigned short* Ag = xb + (size_t)m0 * 832;

    for (int i = tid; i < HH; i += 256) biasL[i] = eb1[i];
    __syncthreads();
    layer<0, true, 5>(tid, Ag, nullptr, w1t, 832, 13, 3, biasL, actP,
                      nullptr, nullptr, nullptr, nullptr, astg, bstg);
    __syncthreads();

    for (int i = tid; i < HH; i += 256) biasL[i] = eb2[i];
    __syncthreads();
    layer<0, false, 4>(tid, nullptr, actP, w2t, 320, 5, 3, biasL, actQ,
                       nullptr, nullptr, nullptr, nullptr, astg, bstg);
    __syncthreads();

    if (tid < 20) biasL[tid] = eb3[tid];
    __syncthreads();
    layer<1, false, 4>(tid, nullptr, actQ, w3t, 320, 5, 1, biasL, nullptr,
                       c3L, nullptr, nullptr, nullptr, astg, bstg);
    __syncthreads();

    { uint4 z; z.x = z.y = z.z = z.w = 0u; reinterpret_cast<uint4*>(fbL)[tid] = z; }
    __syncthreads();
    if (tid < 32) {
        float a = 0.f;
        #pragma unroll
        for (int j = 0; j < ZD; ++j) {
            float qm = c3L[tid * 24 + j];
            float qh = c3L[tid * 24 + 10 + j];
            float qv = sp_(qh) + 1e-8f;
            float e  = eps[(size_t)(m0 + tid) * ZD + j];
            float zj = qm + sqrtf(qv) * e;
            fbw(fbL, tid, j,      bf16_(zj * zj));
            fbw(fbL, tid, 10 + j, bf16_(zj));
            float d = zj - qm;
            a += __logf(6.283185307179586f * qv) + d * d / qv;
        }
        lqzL[tid] = -0.5f * a;
    }
    __syncthreads();

    for (int i = tid; i < HH; i += 256) biasL[i] = db1[i];
    __syncthreads();
    layer<0, false, 4>(tid, nullptr, fbL, d1t, 64, 1, 3, biasL, actP,
                       nullptr, nullptr, nullptr, nullptr, astg, bstg);
    __syncthreads();

    for (int i = tid; i < HH; i += 256) biasL[i] = db2[i];
    __syncthreads();
    layer<0, false, 4>(tid, nullptr, actP, d2t, 320, 5, 3, biasL, actQ,
                       nullptr, nullptr, nullptr, nullptr, astg, bstg);
    __syncthreads();

    for (int i = tid; i < XD; i += 256) biasL[i] = db3[i];
    __syncthreads();
    layer<2, false, 4>(tid, Ag, actQ, d3t, 320, 5, 7, biasL, nullptr,
                       nullptr, redL, nullptr, nullptr, astg, bstg);
    __syncthreads();

    for (int i = tid; i < 2048; i += 256) cbL[i] = cbias[i];
    __syncthreads();
    layer<3, false, 4>(tid, nullptr, fbL, G, 64, 1, 16, cbL, nullptr,
                       nullptr, nullptr, redM, redS, astg, bstg);
    __syncthreads();

    if (tid < 32) {
        float M0 = redM[tid * 4], M1 = redM[tid * 4 + 1], M2 = redM[tid * 4 + 2], M3 = redM[tid * 4 + 3];
        float M = fmaxf(fmaxf(M0, M1), fmaxf(M2, M3));
        float S = redS[tid * 4] * __expf(M0 - M) + redS[tid * 4 + 1] * __expf(M1 - M)
                + redS[tid * 4 + 2] * __expf(M2 - M) + redS[tid * 4 + 3] * __expf(M3 - M);
        float lpz = M + __logf(S) - 7.6009024595420824f;  // log(2000)
        float lpx = redL[tid * 4] + redL[tid * 4 + 1] + redL[tid * 4 + 2] + redL[tid * 4 + 3];
        float kl = lqzL[tid] - lpz;
        float ne = kl - lpx, re = -lpx;
        #pragma unroll
        for (int d = 1; d <= 16; d <<= 1) {
            ne += __shfl_xor(ne, d); kl += __shfl_xor(kl, d); re += __shfl_xor(re, d);
        }
        if (tid == 0) {
            part[blockIdx.x * 3 + 0] = ne;
            part[blockIdx.x * 3 + 1] = kl;
            part[blockIdx.x * 3 + 2] = re;
        }
    }
}

// x[8192][784] fp32 -> xb[8192][832] bf16 zero-padded
__global__ __launch_bounds__(256)
void conv_x_k(const float* __restrict__ x, unsigned short* __restrict__ xb)
{
    int idx = blockIdx.x * 256 + threadIdx.x;
    int r = idx / 208, c4 = (idx - r * 208) * 4;
    if (r >= BB) return;
    unsigned int u0 = 0, u1 = 0;
    if (c4 < XD) {
        float4 v = *reinterpret_cast<const float4*>(&x[(size_t)r * XD + c4]);
        u0 = (unsigned)bf16_(v.x) | ((unsigned)bf16_(v.y) << 16);
        u1 = (unsigned)bf16_(v.z) | ((unsigned)bf16_(v.w) << 16);
    }
    uint2 u; u.x = u0; u.y = u1;
    *reinterpret_cast<uint2*>(&xb[(size_t)r * 832 + c4]) = u;
}

// all weight transposes/pads + GMM coef, selected by blockIdx.y
__global__ __launch_bounds__(256)
void prep_k(const float* __restrict__ ew1, const float* __restrict__ ew2,
            const float* __restrict__ ew3, const float* __restrict__ dw1,
            const float* __restrict__ dw2, const float* __restrict__ dw3,
            const float* __restrict__ zpre,
            unsigned short* __restrict__ w1t, unsigned short* __restrict__ w2t,
            unsigned short* __restrict__ w3t, unsigned short* __restrict__ d1t,
            unsigned short* __restrict__ d2t, unsigned short* __restrict__ d3t,
            unsigned short* __restrict__ G, float* __restrict__ cbias)
{
    const int idx = blockIdx.x * 256 + threadIdx.x;
    const int y = blockIdx.y;
    if (y == 0) {
        if (idx >= 384 * 832) return;
        int n = idx / 832, k = idx - n * 832;
        w1t[idx] = bf16_((n < HH && k < XD) ? ew1[(size_t)k * HH + n] : 0.f);
    } else if (y == 1) {
        if (idx >= 384 * 320) return;
        int n = idx / 320, k = idx - n * 320;
        w2t[idx] = bf16_((n < HH && k < HH) ? ew2[(size_t)k * HH + n] : 0.f);
    } else if (y == 2) {
        if (idx >= 128 * 320) return;
        int n = idx / 320, k = idx - n * 320;
        w3t[idx] = bf16_((n < 2 * ZD && k < HH) ? ew3[(size_t)k * 2 * ZD + n] : 0.f);
    } else if (y == 3) {   // d1t [384][64], dw1 rows at k=10..19 (matches fb layout)
        if (idx >= 384 * 64) return;
        int n = idx / 64, k = idx - n * 64;
        float v = (n < HH && k >= 10 && k < 20) ? dw1[(size_t)(k - 10) * HH + n] : 0.f;
        d1t[idx] = bf16_(v);
    } else if (y == 4) {
        if (idx >= 384 * 320) return;
        int n = idx / 320, k = idx - n * 320;
        d2t[idx] = bf16_((n < HH && k < HH) ? dw2[(size_t)k * HH + n] : 0.f);
    } else if (y == 5) {
        if (idx >= 896 * 320) return;
        int n = idx / 320, k = idx - n * 320;
        d3t[idx] = bf16_((n < XD && k < HH) ? dw3[(size_t)k * XD + n] : 0.f);
    } else {
        if (idx >= 2048) return;
        int k = idx;
        if (k < KK) {
            float csum = 0.f;
            #pragma unroll
            for (int j = 0; j < ZD; ++j) {
                float m = zpre[k * ZD + j];
                float h = zpre[(KK + k) * ZD + j];
                float v = sp_(h) + 1e-8f;
                G[k * 64 + j] = bf16_(-0.5f / v);
                G[k * 64 + 10 + j] = bf16_(m / v);
                csum += __logf(6.283185307179586f * v) + m * m / v;
            }
            #pragma unroll
            for (int j = 20; j < 64; ++j) G[k * 64 + j] = 0;
            cbias[k] = -0.5f * csum;
        } else {
            #pragma unroll
            for (int j = 0; j < 64; ++j) G[k * 64 + j] = 0;
            cbias[k] = -1e30f;
        }
    }
}

__global__ void fin_k(const float* __restrict__ part, float* __restrict__ out)
{
    int t = threadIdx.x;
    if (t < 3) {
        float s = 0.f;
        for (int b = 0; b < 256; ++b) s += part[b * 3 + t];
        out[t] = s / (float)BB;
    }
}

extern "C" void kernel_launch(void* const* d_in, const int* in_sizes, int n_in,
                              void* d_out, int out_size, void* d_ws, size_t ws_size,
                              hipStream_t stream)
{
    const float* x    = (const float*)d_in[0];
    const float* eps  = (const float*)d_in[1];
    const float* zpre = (const float*)d_in[2];
    const float* ew1  = (const float*)d_in[3];
    const float* eb1  = (const float*)d_in[4];
    const float* ew2  = (const float*)d_in[5];
    const float* eb2  = (const float*)d_in[6];
    const float* ew3  = (const float*)d_in[7];
    const float* eb3  = (const float*)d_in[8];
    const float* dw1  = (const float*)d_in[9];
    const float* db1  = (const float*)d_in[10];
    const float* dw2  = (const float*)d_in[11];
    const float* db2  = (const float*)d_in[12];
    const float* dw3  = (const float*)d_in[13];
    const float* db3  = (const float*)d_in[14];
    float* out = (float*)d_out;

    float* ws    = (float*)d_ws;
    float* part  = ws;                       // 768
    float* cbias = part + 768;               // 2048
    unsigned short* ub = (unsigned short*)(cbias + 2048);
    unsigned short* xb  = ub; ub += (size_t)BB * 832;
    unsigned short* w1t = ub; ub += 384 * 832;
    unsigned short* w2t = ub; ub += 384 * 320;
    unsigned short* w3t = ub; ub += 128 * 320;
    unsigned short* d1t = ub; ub += 384 * 64;
    unsigned short* d2t = ub; ub += 384 * 320;
    unsigned short* d3t = ub; ub += 896 * 320;
    unsigned short* G   = ub; ub += 2048 * 64;

    dim3 blk(256);
    conv_x_k<<<(BB * 208) / 256, blk, 0, stream>>>(x, xb);
    prep_k<<<dim3(1248, 7), blk, 0, stream>>>(ew1, ew2, ew3, dw1, dw2, dw3, zpre,
                                              w1t, w2t, w3t, d1t, d2t, d3t, G, cbias);
    fused_k<<<256, blk, 0, stream>>>(xb, w1t, eb1, w2t, eb2, w3t, eb3,
                                     d1t, db1, d2t, db2, d3t, db3, G, cbias, eps, part);
    fin_k<<<1, 64, 0, stream>>>(part, out);
}

// Round 7
// 206.025 us; speedup vs baseline: 1.1380x; 1.1380x over previous
//
#include <hip/hip_runtime.h>
#include <hip/hip_bf16.h>
#include <math.h>

#define BB 8192
#define XD 784
#define ZD 10
#define KK 2000
#define HH 300

typedef short short8 __attribute__((ext_vector_type(8)));
typedef float f32x4 __attribute__((ext_vector_type(4)));

__device__ __forceinline__ float sp_(float x) {
    return fmaxf(x, 0.f) + __logf(1.f + __expf(-fabsf(x)));
}
__device__ __forceinline__ float elu_(float x) { return x > 0.f ? x : __expf(x) - 1.f; }
__device__ __forceinline__ unsigned short bf16_(float v) {
    __hip_bfloat16 h = __float2bfloat16(v);
    return __builtin_bit_cast(unsigned short, h);
}
__device__ __forceinline__ float b2f_(unsigned short u) {
    return __builtin_bit_cast(float, (unsigned int)u << 16);
}
__device__ __forceinline__ void gl16(const unsigned short* g, unsigned short* l) {
    __builtin_amdgcn_global_load_lds(
        (const __attribute__((address_space(1))) unsigned int*)g,
        (__attribute__((address_space(3))) unsigned int*)l, 16, 0, 0);
}
template<int N> __device__ __forceinline__ void vwait() {
    if constexpr (N == 0)  asm volatile("s_waitcnt vmcnt(0)" ::: "memory");
    if constexpr (N == 4)  asm volatile("s_waitcnt vmcnt(4)" ::: "memory");
    if constexpr (N == 5)  asm volatile("s_waitcnt vmcnt(5)" ::: "memory");
    if constexpr (N == 8)  asm volatile("s_waitcnt vmcnt(8)" ::: "memory");
    if constexpr (N == 10) asm volatile("s_waitcnt vmcnt(10)" ::: "memory");
}
// fragment-major write of element (row<16, k) into a 16-row activation buffer:
// slice k>>5, addr = ((k>>5)*64 + row + ((k>>3)&3)*16)*8 + (k&7)
__device__ __forceinline__ void fbw(unsigned short* fb, int row, int k, unsigned short v) {
    fb[(((k >> 5)) * 64 + row + (((k >> 3) & 3) << 4)) * 8 + (k & 7)] = v;
}

// ---------------------------------------------------------------------------
// One fused layer on a 16-row slab: C[16][NI*128] = A[16][KP] @ Wt[.][KP]^T
// 4 waves; wave w owns cols w*32..w*32+31 of each 128-col n-tile (1x2 frags
// of 16x16x32). 3-deep B staging ring via global_load_lds, counted vmcnt
// (SCNT gl16/wave/stage). Step loop is NOT unrolled (I$ residency).
// LMODE 0: bf16 elu -> actout (fragment-major, cols<320, zero-pad >=300)
// LMODE 1: fp32 c3L[row*24+c], c<20
// LMODE 2: per-row sum(x*logit - softplus(logit)) -> redL (vmcnt(0)/step)
// LMODE 3: per-row online logsumexp (c_k folded into B cols 20/21) -> redM/S
// ---------------------------------------------------------------------------
template<int LMODE, bool AGLOB, int SCNT>
__device__ __forceinline__ void layer(
    const int tid, const unsigned short* __restrict__ Ag,
    const unsigned short* __restrict__ actin,
    const unsigned short* __restrict__ Wt, const int KP, const int KI, const int NI,
    const float* __restrict__ bL, unsigned short* __restrict__ actout,
    float* __restrict__ c3L, float* __restrict__ redL,
    float* __restrict__ redM, float* __restrict__ redS,
    unsigned short* __restrict__ astg, unsigned short* __restrict__ bstg)
{
    const int w = tid >> 6, l = tid & 63;
    const int cl = l & 15, g4 = (l >> 4) << 2;
    const int NQ = NI * KI;

    f32x4 acc[2];
    acc[0] = (f32x4){0.f, 0.f, 0.f, 0.f};
    acc[1] = (f32x4){0.f, 0.f, 0.f, 0.f};
    float rA[4], rB[4];
    #pragma unroll
    for (int r = 0; r < 4; ++r) { rA[r] = (LMODE == 3) ? -1e30f : 0.f; rB[r] = 0.f; }

    auto stage = [&](int ni, int ki, int buf) {
        const int n0 = ni * 128, k0 = ki * 64;
        #pragma unroll
        for (int r = 0; r < 4; ++r) {
            const int c0 = r * 256 + w * 64;            // wave-uniform
            const int nc = c0 >> 7, s = (c0 >> 6) & 1;
            const unsigned short* src =
                Wt + (size_t)(n0 + nc * 16 + cl) * KP + k0 + s * 32 + ((l >> 4) << 3);
            gl16(src, bstg + buf * 8192 + c0 * 8);
        }
        if constexpr (AGLOB) {
            const int s = w & 1;                         // waves 0,2 -> half 0; 1,3 -> half 1 (dup ok)
            const unsigned short* src =
                Ag + (size_t)cl * 832 + k0 + s * 32 + ((l >> 4) << 3);
            gl16(src, astg + buf * 1024 + s * 512);
        }
    };
    auto adv = [&](int& ni, int& ki) { if (++ki == KI) { ki = 0; ++ni; } };

    int sni = 0, ski = 0;
    stage(sni, ski, 0); adv(sni, ski);
    stage(sni, ski, 1); adv(sni, ski);
    int cni = 0, cki = 0, cur = 0, pf = 2;

    #pragma unroll 1
    for (int q = 0; q < NQ; ++q) {
        if (q + 2 < NQ) { stage(sni, ski, pf); adv(sni, ski); }
        if constexpr (LMODE == 2) {
            vwait<0>();     // epilogue X loads pollute counting; full drain
        } else {
            const int rem = NQ - 1 - q;
            if (rem >= 2)      vwait<2 * SCNT>();
            else if (rem == 1) vwait<SCNT>();
            else               vwait<0>();
        }
        __builtin_amdgcn_s_barrier();
        __builtin_amdgcn_sched_barrier(0);

        short8 a[2], b[2][2];
        #pragma unroll
        for (int s = 0; s < 2; ++s) {
            if constexpr (AGLOB)
                a[s] = *reinterpret_cast<const short8*>(astg + cur * 1024 + s * 512 + l * 8);
            else
                a[s] = *reinterpret_cast<const short8*>(actin + ((cki * 2 + s) * 64 + l) * 8);
        }
        #pragma unroll
        for (int nj = 0; nj < 2; ++nj)
            #pragma unroll
            for (int s = 0; s < 2; ++s)
                b[nj][s] = *reinterpret_cast<const short8*>(
                    bstg + cur * 8192 + (((w * 2 + nj) * 2 + s) * 64 + l) * 8);
        #pragma unroll
        for (int nj = 0; nj < 2; ++nj) {
            acc[nj] = __builtin_amdgcn_mfma_f32_16x16x32_bf16(a[0], b[nj][0], acc[nj], 0, 0, 0);
            acc[nj] = __builtin_amdgcn_mfma_f32_16x16x32_bf16(a[1], b[nj][1], acc[nj], 0, 0, 0);
        }
        asm volatile("s_waitcnt lgkmcnt(0)" ::: "memory");
        __builtin_amdgcn_sched_barrier(0);
        __builtin_amdgcn_s_barrier();
        __builtin_amdgcn_sched_barrier(0);

        if (cki == KI - 1) {
            const int n0 = cni * 128;
            if (LMODE == 0) {
                #pragma unroll
                for (int nj = 0; nj < 2; ++nj) {
                    const int c = n0 + w * 32 + nj * 16 + cl;
                    const float bb = (c < HH) ? bL[c] : 0.f;
                    #pragma unroll
                    for (int rr = 0; rr < 4; ++rr) {
                        float o = (c < HH) ? elu_(acc[nj][rr] + bb) : 0.f;
                        if (c < 320)
                            actout[((c >> 5) * 64 + (g4 + rr) + (((c >> 3) & 3) << 4)) * 8 + (c & 7)] = bf16_(o);
                    }
                }
            } else if (LMODE == 1) {
                #pragma unroll
                for (int nj = 0; nj < 2; ++nj) {
                    const int c = w * 32 + nj * 16 + cl;
                    if (c < 20) {
                        #pragma unroll
                        for (int rr = 0; rr < 4; ++rr)
                            c3L[(g4 + rr) * 24 + c] = acc[nj][rr] + bL[c];
                    }
                }
            } else if (LMODE == 2) {
                #pragma unroll
                for (int rr = 0; rr < 4; ++rr) {
                    const int row = g4 + rr;
                    float s2 = 0.f;
                    #pragma unroll
                    for (int nj = 0; nj < 2; ++nj) {
                        const int c = n0 + w * 32 + nj * 16 + cl;
                        if (c < XD) {
                            float lv = acc[nj][rr] + bL[c];
                            float xv = b2f_(Ag[(size_t)row * 832 + c]);
                            s2 += xv * lv - sp_(lv);
                        }
                    }
                    s2 += __shfl_xor(s2, 1); s2 += __shfl_xor(s2, 2);
                    s2 += __shfl_xor(s2, 4); s2 += __shfl_xor(s2, 8);
                    rA[rr] += s2;
                }
            } else {
                #pragma unroll
                for (int rr = 0; rr < 4; ++rr) {
                    float v0 = acc[0][rr];
                    float v1 = acc[1][rr];
                    float mx = fmaxf(v0, v1);
                    mx = fmaxf(mx, __shfl_xor(mx, 1)); mx = fmaxf(mx, __shfl_xor(mx, 2));
                    mx = fmaxf(mx, __shfl_xor(mx, 4)); mx = fmaxf(mx, __shfl_xor(mx, 8));
                    float s = __expf(v0 - mx) + __expf(v1 - mx);
                    s += __shfl_xor(s, 1); s += __shfl_xor(s, 2);
                    s += __shfl_xor(s, 4); s += __shfl_xor(s, 8);
                    if (mx > rA[rr]) { rB[rr] = rB[rr] * __expf(rA[rr] - mx) + s; rA[rr] = mx; }
                    else             { rB[rr] += s * __expf(mx - rA[rr]); }
                }
            }
            acc[0] = (f32x4){0.f, 0.f, 0.f, 0.f};
            acc[1] = (f32x4){0.f, 0.f, 0.f, 0.f};
        }
        adv(cni, cki);
        cur = (cur + 1 < 3) ? cur + 1 : 0;
        pf  = (pf  + 1 < 3) ? pf  + 1 : 0;
    }
    if (LMODE == 2 && cl == 0) {
        #pragma unroll
        for (int rr = 0; rr < 4; ++rr) redL[(g4 + rr) * 4 + w] = rA[rr];
    }
    if (LMODE == 3 && cl == 0) {
        #pragma unroll
        for (int rr = 0; rr < 4; ++rr) {
            redM[(g4 + rr) * 4 + w] = rA[rr];
            redS[(g4 + rr) * 4 + w] = rB[rr];
        }
    }
}

__global__ __launch_bounds__(256, 2)
void fused_k(const unsigned short* __restrict__ xb,
             const unsigned short* __restrict__ w1t, const float* __restrict__ eb1,
             const unsigned short* __restrict__ w2t, const float* __restrict__ eb2,
             const unsigned short* __restrict__ w3t, const float* __restrict__ eb3,
             const unsigned short* __restrict__ d1t, const float* __restrict__ db1,
             const unsigned short* __restrict__ d2t, const float* __restrict__ db2,
             const unsigned short* __restrict__ d3t, const float* __restrict__ db3,
             const unsigned short* __restrict__ G,
             const float* __restrict__ eps, float* __restrict__ part)
{
    __shared__ __align__(16) unsigned short actP[5120];
    __shared__ __align__(16) unsigned short uQ[5120];       // actQ; astg alias (enc1 only)
    __shared__ __align__(16) unsigned short bstg[24576];
    __shared__ __align__(16) unsigned short fbL[1024];
    __shared__ float biasF[896];                             // bias[0..511]; c3L at +512
    __shared__ float redM[64], redS[64], redL[64], lqzL[16];

    const int tid = threadIdx.x;
    const int m0 = blockIdx.x * 16;
    const unsigned short* Ag = xb + (size_t)m0 * 832;
    float* c3L = biasF + 512;

    for (int i = tid; i < HH; i += 256) biasF[i] = eb1[i];
    __syncthreads();
    layer<0, true, 5>(tid, Ag, nullptr, w1t, 832, 13, 3, biasF, actP,
                      nullptr, nullptr, nullptr, nullptr, uQ, bstg);
    __syncthreads();

    for (int i = tid; i < HH; i += 256) biasF[i] = eb2[i];
    __syncthreads();
    layer<0, false, 4>(tid, nullptr, actP, w2t, 320, 5, 3, biasF, uQ,
                       nullptr, nullptr, nullptr, nullptr, nullptr, bstg);
    __syncthreads();

    if (tid < 20) biasF[tid] = eb3[tid];
    __syncthreads();
    layer<1, false, 4>(tid, nullptr, uQ, w3t, 320, 5, 1, biasF, nullptr,
                       c3L, nullptr, nullptr, nullptr, nullptr, bstg);
    __syncthreads();

    if (tid < 128) reinterpret_cast<uint4*>(fbL)[tid] = (uint4){0u, 0u, 0u, 0u};
    __syncthreads();
    if (tid < 16) {
        float a = 0.f;
        #pragma unroll
        for (int j = 0; j < ZD; ++j) {
            float qm = c3L[tid * 24 + j];
            float qh = c3L[tid * 24 + 10 + j];
            float qv = sp_(qh) + 1e-8f;
            float e  = eps[(size_t)(m0 + tid) * ZD + j];
            float zj = qm + sqrtf(qv) * e;
            fbw(fbL, tid, j,      bf16_(zj * zj));
            fbw(fbL, tid, 10 + j, bf16_(zj));
            float d = zj - qm;
            a += __logf(6.283185307179586f * qv) + d * d / qv;
        }
        fbw(fbL, tid, 20, bf16_(1.f));   // carries c_k (hi/lo in G cols 20/21)
        fbw(fbL, tid, 21, bf16_(1.f));
        lqzL[tid] = -0.5f * a;
    }
    __syncthreads();

    for (int i = tid; i < HH; i += 256) biasF[i] = db1[i];
    __syncthreads();
    layer<0, false, 4>(tid, nullptr, fbL, d1t, 64, 1, 3, biasF, actP,
                       nullptr, nullptr, nullptr, nullptr, nullptr, bstg);
    __syncthreads();

    for (int i = tid; i < HH; i += 256) biasF[i] = db2[i];
    __syncthreads();
    layer<0, false, 4>(tid, nullptr, actP, d2t, 320, 5, 3, biasF, uQ,
                       nullptr, nullptr, nullptr, nullptr, nullptr, bstg);
    __syncthreads();

    for (int i = tid; i < XD; i += 256) biasF[i] = db3[i];
    __syncthreads();
    layer<2, false, 4>(tid, Ag, uQ, d3t, 320, 5, 7, biasF, nullptr,
                       nullptr, redL, nullptr, nullptr, nullptr, bstg);
    __syncthreads();

    layer<3, false, 4>(tid, nullptr, fbL, G, 64, 1, 16, nullptr, nullptr,
                       nullptr, nullptr, redM, redS, nullptr, bstg);
    __syncthreads();

    if (tid < 16) {
        float M0 = redM[tid * 4], M1 = redM[tid * 4 + 1];
        float M2 = redM[tid * 4 + 2], M3 = redM[tid * 4 + 3];
        float M = fmaxf(fmaxf(M0, M1), fmaxf(M2, M3));
        float S = redS[tid * 4] * __expf(M0 - M) + redS[tid * 4 + 1] * __expf(M1 - M)
                + redS[tid * 4 + 2] * __expf(M2 - M) + redS[tid * 4 + 3] * __expf(M3 - M);
        float lpz = M + __logf(S) - 7.6009024595420824f;  // log(2000)
        float lpx = redL[tid * 4] + redL[tid * 4 + 1] + redL[tid * 4 + 2] + redL[tid * 4 + 3];
        float kl = lqzL[tid] - lpz;
        float ne = kl - lpx, re = -lpx;
        #pragma unroll
        for (int d = 1; d <= 8; d <<= 1) {
            ne += __shfl_xor(ne, d); kl += __shfl_xor(kl, d); re += __shfl_xor(re, d);
        }
        if (tid == 0) {
            part[blockIdx.x * 3 + 0] = ne;
            part[blockIdx.x * 3 + 1] = kl;
            part[blockIdx.x * 3 + 2] = re;
        }
    }
}

// x[8192][784] fp32 -> xb[8192][832] bf16 zero-padded
__global__ __launch_bounds__(256)
void conv_x_k(const float* __restrict__ x, unsigned short* __restrict__ xb)
{
    int idx = blockIdx.x * 256 + threadIdx.x;
    int r = idx / 208, c4 = (idx - r * 208) * 4;
    if (r >= BB) return;
    unsigned int u0 = 0, u1 = 0;
    if (c4 < XD) {
        float4 v = *reinterpret_cast<const float4*>(&x[(size_t)r * XD + c4]);
        u0 = (unsigned)bf16_(v.x) | ((unsigned)bf16_(v.y) << 16);
        u1 = (unsigned)bf16_(v.z) | ((unsigned)bf16_(v.w) << 16);
    }
    uint2 u; u.x = u0; u.y = u1;
    *reinterpret_cast<uint2*>(&xb[(size_t)r * 832 + c4]) = u;
}

// weight transposes/pads + GMM coef matrix (c_k folded as bf16 hi/lo cols)
__global__ __launch_bounds__(256)
void prep_k(const float* __restrict__ ew1, const float* __restrict__ ew2,
            const float* __restrict__ ew3, const float* __restrict__ dw1,
            const float* __restrict__ dw2, const float* __restrict__ dw3,
            const float* __restrict__ zpre,
            unsigned short* __restrict__ w1t, unsigned short* __restrict__ w2t,
            unsigned short* __restrict__ w3t, unsigned short* __restrict__ d1t,
            unsigned short* __restrict__ d2t, unsigned short* __restrict__ d3t,
            unsigned short* __restrict__ G)
{
    const int idx = blockIdx.x * 256 + threadIdx.x;
    const int y = blockIdx.y;
    if (y == 0) {
        if (idx >= 384 * 832) return;
        int n = idx / 832, k = idx - n * 832;
        w1t[idx] = bf16_((n < HH && k < XD) ? ew1[(size_t)k * HH + n] : 0.f);
    } else if (y == 1) {
        if (idx >= 384 * 320) return;
        int n = idx / 320, k = idx - n * 320;
        w2t[idx] = bf16_((n < HH && k < HH) ? ew2[(size_t)k * HH + n] : 0.f);
    } else if (y == 2) {
        if (idx >= 128 * 320) return;
        int n = idx / 320, k = idx - n * 320;
        w3t[idx] = bf16_((n < 2 * ZD && k < HH) ? ew3[(size_t)k * 2 * ZD + n] : 0.f);
    } else if (y == 3) {   // d1t [384][64]; dw1 rows at k=10..19 (fb layout: z at 10..19)
        if (idx >= 384 * 64) return;
        int n = idx / 64, k = idx - n * 64;
        float v = (n < HH && k >= 10 && k < 20) ? dw1[(size_t)(k - 10) * HH + n] : 0.f;
        d1t[idx] = bf16_(v);
    } else if (y == 4) {
        if (idx >= 384 * 320) return;
        int n = idx / 320, k = idx - n * 320;
        d2t[idx] = bf16_((n < HH && k < HH) ? dw2[(size_t)k * HH + n] : 0.f);
    } else if (y == 5) {
        if (idx >= 896 * 320) return;
        int n = idx / 320, k = idx - n * 320;
        d3t[idx] = bf16_((n < XD && k < HH) ? dw3[(size_t)k * XD + n] : 0.f);
    } else {
        if (idx >= 2048) return;
        int k = idx;
        if (k < KK) {
            float csum = 0.f;
            #pragma unroll
            for (int j = 0; j < ZD; ++j) {
                float m = zpre[k * ZD + j];
                float h = zpre[(KK + k) * ZD + j];
                float v = sp_(h) + 1e-8f;
                G[k * 64 + j] = bf16_(-0.5f / v);
                G[k * 64 + 10 + j] = bf16_(m / v);
                csum += __logf(6.283185307179586f * v) + m * m / v;
            }
            float ck = -0.5f * csum;
            unsigned short hi = bf16_(ck);
            G[k * 64 + 20] = hi;
            G[k * 64 + 21] = bf16_(ck - b2f_(hi));
            #pragma unroll
            for (int j = 22; j < 64; ++j) G[k * 64 + j] = 0;
        } else {
            G[k * 64 + 20] = bf16_(-1e30f);
            #pragma unroll
            for (int j = 0; j < 20; ++j) G[k * 64 + j] = 0;
            G[k * 64 + 21] = 0;
            #pragma unroll
            for (int j = 22; j < 64; ++j) G[k * 64 + j] = 0;
        }
    }
}

__global__ void fin_k(const float* __restrict__ part, float* __restrict__ out)
{
    int t = threadIdx.x;
    if (t < 3) {
        float s = 0.f;
        for (int b = 0; b < 512; ++b) s += part[b * 3 + t];
        out[t] = s / (float)BB;
    }
}

extern "C" void kernel_launch(void* const* d_in, const int* in_sizes, int n_in,
                              void* d_out, int out_size, void* d_ws, size_t ws_size,
                              hipStream_t stream)
{
    const float* x    = (const float*)d_in[0];
    const float* eps  = (const float*)d_in[1];
    const float* zpre = (const float*)d_in[2];
    const float* ew1  = (const float*)d_in[3];
    const float* eb1  = (const float*)d_in[4];
    const float* ew2  = (const float*)d_in[5];
    const float* eb2  = (const float*)d_in[6];
    const float* ew3  = (const float*)d_in[7];
    const float* eb3  = (const float*)d_in[8];
    const float* dw1  = (const float*)d_in[9];
    const float* db1  = (const float*)d_in[10];
    const float* dw2  = (const float*)d_in[11];
    const float* db2  = (const float*)d_in[12];
    const float* dw3  = (const float*)d_in[13];
    const float* db3  = (const float*)d_in[14];
    float* out = (float*)d_out;

    float* ws   = (float*)d_ws;
    float* part = ws;                        // 512*3
    unsigned short* ub = (unsigned short*)(part + 1536);
    unsigned short* xb  = ub; ub += (size_t)BB * 832;
    unsigned short* w1t = ub; ub += 384 * 832;
    unsigned short* w2t = ub; ub += 384 * 320;
    unsigned short* w3t = ub; ub += 128 * 320;
    unsigned short* d1t = ub; ub += 384 * 64;
    unsigned short* d2t = ub; ub += 384 * 320;
    unsigned short* d3t = ub; ub += 896 * 320;
    unsigned short* G   = ub; ub += 2048 * 64;

    dim3 blk(256);
    conv_x_k<<<(BB * 208) / 256, blk, 0, stream>>>(x, xb);
    prep_k<<<dim3(1248, 7), blk, 0, stream>>>(ew1, ew2, ew3, dw1, dw2, dw3, zpre,
                                              w1t, w2t, w3t, d1t, d2t, d3t, G);
    fused_k<<<512, blk, 0, stream>>>(xb, w1t, eb1, w2t, eb2, w3t, eb3,
                                     d1t, db1, d2t, db2, d3t, db3, G, eps, part);
    fin_k<<<1, 64, 0, stream>>>(part, out);
}

// Round 8
// 161.222 us; speedup vs baseline: 1.4543x; 1.2779x over previous
//
#include <hip/hip_runtime.h>
#include <hip/hip_bf16.h>
#include <math.h>

#define BB 8192
#define XD 784
#define ZD 10
#define KK 2000
#define HH 300

typedef short short8 __attribute__((ext_vector_type(8)));
typedef float f32x4 __attribute__((ext_vector_type(4)));

__device__ __forceinline__ float sp_(float x) {
    return fmaxf(x, 0.f) + __logf(1.f + __expf(-fabsf(x)));
}
__device__ __forceinline__ float elu_(float x) { return x > 0.f ? x : __expf(x) - 1.f; }
__device__ __forceinline__ unsigned short bf16_(float v) {
    __hip_bfloat16 h = __float2bfloat16(v);
    return __builtin_bit_cast(unsigned short, h);
}
__device__ __forceinline__ float b2f_(unsigned short u) {
    return __builtin_bit_cast(float, (unsigned int)u << 16);
}
__device__ __forceinline__ void gl16(const unsigned short* g, unsigned short* l) {
    __builtin_amdgcn_global_load_lds(
        (const __attribute__((address_space(1))) unsigned int*)g,
        (__attribute__((address_space(3))) unsigned int*)l, 16, 0, 0);
}
// fragment-major write of element (row<16, k): slice k>>5, lane = row + ((k>>3)&3)*16
__device__ __forceinline__ void fbw(unsigned short* fb, int row, int k, unsigned short v) {
    fb[(((k >> 5)) * 64 + row + (((k >> 3) & 3) << 4)) * 8 + (k & 7)] = v;
}

// Load one wave's B fragments (32 cols x 64 k) for step q directly to VGPRs.
// lane l supplies col (l&15), k-slice (l>>4)*8 — consistent with the A-frag
// k-map, and the 4 hi-groups of a col read one contiguous 64B line.
template<int KP, int KI>
__device__ __forceinline__ void ldB(const unsigned short* __restrict__ bbase,
                                    int q, short8 (&f)[2][2]) {
    const int ki = q % KI, ni = q / KI;
    const unsigned short* p = bbase + (size_t)ni * (128 * KP) + ki * 64;
    f[0][0] = *reinterpret_cast<const short8*>(p);
    f[0][1] = *reinterpret_cast<const short8*>(p + 32);
    f[1][0] = *reinterpret_cast<const short8*>(p + 16 * KP);
    f[1][1] = *reinterpret_cast<const short8*>(p + 16 * KP + 32);
}

// ---------------------------------------------------------------------------
// One fused layer on a 16-row slab: C[16][NI*128] = A[16][KP] @ Wt[.][KP]^T
// 4 waves, NO intra-layer barriers: wave w owns cols {ni*128 + w*32 ..+31},
// B direct global->VGPR (depth-1 prefetch, even/odd buffers), A from LDS
// (read-only; fragment-major). All dims compile-time.
// LMODE 0: bf16 elu -> actout. LMODE 1: fp32 c3L (c<20).
// LMODE 2: per-row sum(x*logit - softplus(logit)) -> redL.
// LMODE 3: per-row online logsumexp (c_k folded in B cols 20/21) -> redM/S.
// ---------------------------------------------------------------------------
template<int LMODE, int KP, int KI, int NI>
__device__ __forceinline__ void layer(
    const int tid,
    const unsigned short* __restrict__ Ag,     // x slab base (LMODE 2 epilogue)
    const unsigned short* __restrict__ actin,  // LDS, fragment-major, KP/32 slices
    const unsigned short* __restrict__ Wt,
    const float* __restrict__ bL,
    unsigned short* __restrict__ actout,
    float* __restrict__ c3L, float* __restrict__ redL,
    float* __restrict__ redM, float* __restrict__ redS)
{
    const int w = tid >> 6, l = tid & 63;
    const int cl = l & 15, hi = l >> 4, g4 = hi << 2;
    constexpr int NQ = KI * NI;
    const unsigned short* bbase = Wt + (size_t)(w * 32 + cl) * KP + hi * 8;

    f32x4 acc0 = (f32x4){0.f, 0.f, 0.f, 0.f};
    f32x4 acc1 = (f32x4){0.f, 0.f, 0.f, 0.f};
    float rA[4], rB[4];
    #pragma unroll
    for (int r = 0; r < 4; ++r) { rA[r] = (LMODE == 3) ? -1e30f : 0.f; rB[r] = 0.f; }

    auto step = [&](int q, short8 (&bf)[2][2]) {
        const int cki = q % KI;
        short8 a0 = *reinterpret_cast<const short8*>(actin + ((cki * 2 + 0) * 64 + l) * 8);
        short8 a1 = *reinterpret_cast<const short8*>(actin + ((cki * 2 + 1) * 64 + l) * 8);
        acc0 = __builtin_amdgcn_mfma_f32_16x16x32_bf16(a0, bf[0][0], acc0, 0, 0, 0);
        acc0 = __builtin_amdgcn_mfma_f32_16x16x32_bf16(a1, bf[0][1], acc0, 0, 0, 0);
        acc1 = __builtin_amdgcn_mfma_f32_16x16x32_bf16(a0, bf[1][0], acc1, 0, 0, 0);
        acc1 = __builtin_amdgcn_mfma_f32_16x16x32_bf16(a1, bf[1][1], acc1, 0, 0, 0);
        if (cki == KI - 1) {
            const int n0 = (q / KI) * 128;
            if constexpr (LMODE == 0) {
                {
                    const int c = n0 + w * 32 + cl;
                    const float bb = (c < HH) ? bL[c] : 0.f;
                    #pragma unroll
                    for (int rr = 0; rr < 4; ++rr) {
                        float o = (c < HH) ? elu_(acc0[rr] + bb) : 0.f;
                        if (c < 320)
                            actout[((c >> 5) * 64 + (g4 + rr) + (((c >> 3) & 3) << 4)) * 8 + (c & 7)] = bf16_(o);
                    }
                }
                {
                    const int c = n0 + w * 32 + 16 + cl;
                    const float bb = (c < HH) ? bL[c] : 0.f;
                    #pragma unroll
                    for (int rr = 0; rr < 4; ++rr) {
                        float o = (c < HH) ? elu_(acc1[rr] + bb) : 0.f;
                        if (c < 320)
                            actout[((c >> 5) * 64 + (g4 + rr) + (((c >> 3) & 3) << 4)) * 8 + (c & 7)] = bf16_(o);
                    }
                }
            } else if constexpr (LMODE == 1) {
                {
                    const int c = w * 32 + cl;
                    if (c < 20) {
                        #pragma unroll
                        for (int rr = 0; rr < 4; ++rr)
                            c3L[(g4 + rr) * 24 + c] = acc0[rr] + bL[c];
                    }
                }
                {
                    const int c = w * 32 + 16 + cl;
                    if (c < 20) {
                        #pragma unroll
                        for (int rr = 0; rr < 4; ++rr)
                            c3L[(g4 + rr) * 24 + c] = acc1[rr] + bL[c];
                    }
                }
            } else if constexpr (LMODE == 2) {
                #pragma unroll
                for (int rr = 0; rr < 4; ++rr) {
                    const int row = g4 + rr;
                    float s2 = 0.f;
                    {
                        const int c = n0 + w * 32 + cl;
                        if (c < XD) {
                            float lv = acc0[rr] + bL[c];
                            s2 += b2f_(Ag[(size_t)row * 832 + c]) * lv - sp_(lv);
                        }
                    }
                    {
                        const int c = n0 + w * 32 + 16 + cl;
                        if (c < XD) {
                            float lv = acc1[rr] + bL[c];
                            s2 += b2f_(Ag[(size_t)row * 832 + c]) * lv - sp_(lv);
                        }
                    }
                    s2 += __shfl_xor(s2, 1); s2 += __shfl_xor(s2, 2);
                    s2 += __shfl_xor(s2, 4); s2 += __shfl_xor(s2, 8);
                    rA[rr] += s2;
                }
            } else {
                #pragma unroll
                for (int rr = 0; rr < 4; ++rr) {
                    float v0 = acc0[rr];
                    float v1 = acc1[rr];
                    float mx = fmaxf(v0, v1);
                    mx = fmaxf(mx, __shfl_xor(mx, 1)); mx = fmaxf(mx, __shfl_xor(mx, 2));
                    mx = fmaxf(mx, __shfl_xor(mx, 4)); mx = fmaxf(mx, __shfl_xor(mx, 8));
                    float s = __expf(v0 - mx) + __expf(v1 - mx);
                    s += __shfl_xor(s, 1); s += __shfl_xor(s, 2);
                    s += __shfl_xor(s, 4); s += __shfl_xor(s, 8);
                    if (mx > rA[rr]) { rB[rr] = rB[rr] * __expf(rA[rr] - mx) + s; rA[rr] = mx; }
                    else             { rB[rr] += s * __expf(mx - rA[rr]); }
                }
            }
            acc0 = (f32x4){0.f, 0.f, 0.f, 0.f};
            acc1 = (f32x4){0.f, 0.f, 0.f, 0.f};
        }
    };

    short8 bX[2][2], bY[2][2];
    ldB<KP, KI>(bbase, 0, bX);
    int q = 0;
    #pragma unroll 1
    while (q + 2 <= NQ) {
        ldB<KP, KI>(bbase, q + 1, bY);
        step(q, bX);
        if (q + 2 < NQ) ldB<KP, KI>(bbase, q + 2, bX);
        step(q + 1, bY);
        q += 2;
    }
    if (q < NQ) step(q, bX);

    if (LMODE == 2 && cl == 0) {
        #pragma unroll
        for (int rr = 0; rr < 4; ++rr) redL[(g4 + rr) * 4 + w] = rA[rr];
    }
    if (LMODE == 3 && cl == 0) {
        #pragma unroll
        for (int rr = 0; rr < 4; ++rr) {
            redM[(g4 + rr) * 4 + w] = rA[rr];
            redS[(g4 + rr) * 4 + w] = rB[rr];
        }
    }
}

__global__ __launch_bounds__(256, 3)
void fused_k(const unsigned short* __restrict__ xb,
             const unsigned short* __restrict__ w1t, const float* __restrict__ eb1,
             const unsigned short* __restrict__ w2t, const float* __restrict__ eb2,
             const unsigned short* __restrict__ w3t, const float* __restrict__ eb3,
             const unsigned short* __restrict__ d1t, const float* __restrict__ db1,
             const unsigned short* __restrict__ d2t, const float* __restrict__ db2,
             const unsigned short* __restrict__ d3t, const float* __restrict__ db3,
             const unsigned short* __restrict__ G,
             const float* __restrict__ eps, float* __restrict__ part)
{
    __shared__ __align__(16) unsigned short actP[5120];
    __shared__ __align__(16) unsigned short uQ[13312];   // enc1 A-stage; later actQ
    __shared__ __align__(16) unsigned short fbL[1024];
    __shared__ float biasF[896];                          // bias; c3L at +512
    __shared__ float redM[64], redS[64], redL[64], lqzL[16];

    const int tid = threadIdx.x;
    const int w = tid >> 6, l = tid & 63;
    const int cl = l & 15, hi = l >> 4;
    const int m0 = blockIdx.x * 16;
    const unsigned short* Ag = xb + (size_t)m0 * 832;
    float* c3L = biasF + 512;

    // stage enc1's A (16x832) into uQ once; load eb1; one barrier
    for (int j = w; j < 26; j += 4)
        gl16(Ag + (size_t)cl * 832 + j * 32 + hi * 8, uQ + j * 512);
    for (int i = tid; i < HH; i += 256) biasF[i] = eb1[i];
    asm volatile("s_waitcnt vmcnt(0)" ::: "memory");
    __syncthreads();
    layer<0, 832, 13, 3>(tid, Ag, uQ, w1t, biasF, actP, nullptr, nullptr, nullptr, nullptr);
    __syncthreads();

    for (int i = tid; i < HH; i += 256) biasF[i] = eb2[i];
    __syncthreads();
    layer<0, 320, 5, 3>(tid, Ag, actP, w2t, biasF, uQ, nullptr, nullptr, nullptr, nullptr);
    __syncthreads();

    if (tid < 20) biasF[tid] = eb3[tid];
    __syncthreads();
    layer<1, 320, 5, 1>(tid, Ag, uQ, w3t, biasF, nullptr, c3L, nullptr, nullptr, nullptr);
    __syncthreads();

    if (tid < 128) reinterpret_cast<uint4*>(fbL)[tid] = (uint4){0u, 0u, 0u, 0u};
    __syncthreads();
    if (tid < 16) {
        float a = 0.f;
        #pragma unroll
        for (int j = 0; j < ZD; ++j) {
            float qm = c3L[tid * 24 + j];
            float qh = c3L[tid * 24 + 10 + j];
            float qv = sp_(qh) + 1e-8f;
            float e  = eps[(size_t)(m0 + tid) * ZD + j];
            float zj = qm + sqrtf(qv) * e;
            fbw(fbL, tid, j,      bf16_(zj * zj));
            fbw(fbL, tid, 10 + j, bf16_(zj));
            float d = zj - qm;
            a += __logf(6.283185307179586f * qv) + d * d / qv;
        }
        fbw(fbL, tid, 20, bf16_(1.f));   // picks up c_k hi/lo from G cols 20/21
        fbw(fbL, tid, 21, bf16_(1.f));
        lqzL[tid] = -0.5f * a;
    }
    __syncthreads();

    for (int i = tid; i < HH; i += 256) biasF[i] = db1[i];
    __syncthreads();
    layer<0, 64, 1, 3>(tid, Ag, fbL, d1t, biasF, actP, nullptr, nullptr, nullptr, nullptr);
    __syncthreads();

    for (int i = tid; i < HH; i += 256) biasF[i] = db2[i];
    __syncthreads();
    layer<0, 320, 5, 3>(tid, Ag, actP, d2t, biasF, uQ, nullptr, nullptr, nullptr, nullptr);
    __syncthreads();

    for (int i = tid; i < XD; i += 256) biasF[i] = db3[i];
    __syncthreads();
    layer<2, 320, 5, 7>(tid, Ag, uQ, d3t, biasF, nullptr, nullptr, redL, nullptr, nullptr);
    __syncthreads();

    layer<3, 64, 1, 16>(tid, Ag, fbL, G, nullptr, nullptr, nullptr, nullptr, redM, redS);
    __syncthreads();

    if (tid < 16) {
        float M0 = redM[tid * 4], M1 = redM[tid * 4 + 1];
        float M2 = redM[tid * 4 + 2], M3 = redM[tid * 4 + 3];
        float M = fmaxf(fmaxf(M0, M1), fmaxf(M2, M3));
        float S = redS[tid * 4] * __expf(M0 - M) + redS[tid * 4 + 1] * __expf(M1 - M)
                + redS[tid * 4 + 2] * __expf(M2 - M) + redS[tid * 4 + 3] * __expf(M3 - M);
        float lpz = M + __logf(S) - 7.6009024595420824f;  // log(2000)
        float lpx = redL[tid * 4] + redL[tid * 4 + 1] + redL[tid * 4 + 2] + redL[tid * 4 + 3];
        float kl = lqzL[tid] - lpz;
        float ne = kl - lpx, re = -lpx;
        #pragma unroll
        for (int d = 1; d <= 8; d <<= 1) {
            ne += __shfl_xor(ne, d); kl += __shfl_xor(kl, d); re += __shfl_xor(re, d);
        }
        if (tid == 0) {
            part[blockIdx.x * 3 + 0] = ne;
            part[blockIdx.x * 3 + 1] = kl;
            part[blockIdx.x * 3 + 2] = re;
        }
    }
}

// x[8192][784] fp32 -> xb[8192][832] bf16 zero-padded
__global__ __launch_bounds__(256)
void conv_x_k(const float* __restrict__ x, unsigned short* __restrict__ xb)
{
    int idx = blockIdx.x * 256 + threadIdx.x;
    int r = idx / 208, c4 = (idx - r * 208) * 4;
    if (r >= BB) return;
    unsigned int u0 = 0, u1 = 0;
    if (c4 < XD) {
        float4 v = *reinterpret_cast<const float4*>(&x[(size_t)r * XD + c4]);
        u0 = (unsigned)bf16_(v.x) | ((unsigned)bf16_(v.y) << 16);
        u1 = (unsigned)bf16_(v.z) | ((unsigned)bf16_(v.w) << 16);
    }
    uint2 u; u.x = u0; u.y = u1;
    *reinterpret_cast<uint2*>(&xb[(size_t)r * 832 + c4]) = u;
}

// weight transposes/pads + GMM coef matrix (c_k folded as bf16 hi/lo cols)
__global__ __launch_bounds__(256)
void prep_k(const float* __restrict__ ew1, const float* __restrict__ ew2,
            const float* __restrict__ ew3, const float* __restrict__ dw1,
            const float* __restrict__ dw2, const float* __restrict__ dw3,
            const float* __restrict__ zpre,
            unsigned short* __restrict__ w1t, unsigned short* __restrict__ w2t,
            unsigned short* __restrict__ w3t, unsigned short* __restrict__ d1t,
            unsigned short* __restrict__ d2t, unsigned short* __restrict__ d3t,
            unsigned short* __restrict__ G)
{
    const int idx = blockIdx.x * 256 + threadIdx.x;
    const int y = blockIdx.y;
    if (y == 0) {
        if (idx >= 384 * 832) return;
        int n = idx / 832, k = idx - n * 832;
        w1t[idx] = bf16_((n < HH && k < XD) ? ew1[(size_t)k * HH + n] : 0.f);
    } else if (y == 1) {
        if (idx >= 384 * 320) return;
        int n = idx / 320, k = idx - n * 320;
        w2t[idx] = bf16_((n < HH && k < HH) ? ew2[(size_t)k * HH + n] : 0.f);
    } else if (y == 2) {
        if (idx >= 128 * 320) return;
        int n = idx / 320, k = idx - n * 320;
        w3t[idx] = bf16_((n < 2 * ZD && k < HH) ? ew3[(size_t)k * 2 * ZD + n] : 0.f);
    } else if (y == 3) {   // d1t [384][64]; dw1 rows at k=10..19 (fb layout: z at 10..19)
        if (idx >= 384 * 64) return;
        int n = idx / 64, k = idx - n * 64;
        float v = (n < HH && k >= 10 && k < 20) ? dw1[(size_t)(k - 10) * HH + n] : 0.f;
        d1t[idx] = bf16_(v);
    } else if (y == 4) {
        if (idx >= 384 * 320) return;
        int n = idx / 320, k = idx - n * 320;
        d2t[idx] = bf16_((n < HH && k < HH) ? dw2[(size_t)k * HH + n] : 0.f);
    } else if (y == 5) {
        if (idx >= 896 * 320) return;
        int n = idx / 320, k = idx - n * 320;
        d3t[idx] = bf16_((n < XD && k < HH) ? dw3[(size_t)k * XD + n] : 0.f);
    } else {
        if (idx >= 2048) return;
        int k = idx;
        if (k < KK) {
            float csum = 0.f;
            #pragma unroll
            for (int j = 0; j < ZD; ++j) {
                float m = zpre[k * ZD + j];
                float h = zpre[(KK + k) * ZD + j];
                float v = sp_(h) + 1e-8f;
                G[k * 64 + j] = bf16_(-0.5f / v);
                G[k * 64 + 10 + j] = bf16_(m / v);
                csum += __logf(6.283185307179586f * v) + m * m / v;
            }
            float ck = -0.5f * csum;
            unsigned short hic = bf16_(ck);
            G[k * 64 + 20] = hic;
            G[k * 64 + 21] = bf16_(ck - b2f_(hic));
            #pragma unroll
            for (int j = 22; j < 64; ++j) G[k * 64 + j] = 0;
        } else {
            #pragma unroll
            for (int j = 0; j < 20; ++j) G[k * 64 + j] = 0;
            G[k * 64 + 20] = bf16_(-1e30f);
            G[k * 64 + 21] = 0;
            #pragma unroll
            for (int j = 22; j < 64; ++j) G[k * 64 + j] = 0;
        }
    }
}

__global__ void fin_k(const float* __restrict__ part, float* __restrict__ out)
{
    int c = threadIdx.x >> 6, l = threadIdx.x & 63;
    if (c < 3) {
        float s = 0.f;
        for (int i = l; i < 512; i += 64) s += part[i * 3 + c];
        #pragma unroll
        for (int d = 1; d < 64; d <<= 1) s += __shfl_xor(s, d);
        if (l == 0) out[c] = s / (float)BB;
    }
}

extern "C" void kernel_launch(void* const* d_in, const int* in_sizes, int n_in,
                              void* d_out, int out_size, void* d_ws, size_t ws_size,
                              hipStream_t stream)
{
    const float* x    = (const float*)d_in[0];
    const float* eps  = (const float*)d_in[1];
    const float* zpre = (const float*)d_in[2];
    const float* ew1  = (const float*)d_in[3];
    const float* eb1  = (const float*)d_in[4];
    const float* ew2  = (const float*)d_in[5];
    const float* eb2  = (const float*)d_in[6];
    const float* ew3  = (const float*)d_in[7];
    const float* eb3  = (const float*)d_in[8];
    const float* dw1  = (const float*)d_in[9];
    const float* db1  = (const float*)d_in[10];
    const float* dw2  = (const float*)d_in[11];
    const float* db2  = (const float*)d_in[12];
    const float* dw3  = (const float*)d_in[13];
    const float* db3  = (const float*)d_in[14];
    float* out = (float*)d_out;

    float* ws   = (float*)d_ws;
    float* part = ws;                        // 512*3
    unsigned short* ub = (unsigned short*)(part + 1536);
    unsigned short* xb  = ub; ub += (size_t)BB * 832;
    unsigned short* w1t = ub; ub += 384 * 832;
    unsigned short* w2t = ub; ub += 384 * 320;
    unsigned short* w3t = ub; ub += 128 * 320;
    unsigned short* d1t = ub; ub += 384 * 64;
    unsigned short* d2t = ub; ub += 384 * 320;
    unsigned short* d3t = ub; ub += 896 * 320;
    unsigned short* G   = ub; ub += 2048 * 64;

    dim3 blk(256);
    conv_x_k<<<(BB * 208) / 256, blk, 0, stream>>>(x, xb);
    prep_k<<<dim3(1248, 7), blk, 0, stream>>>(ew1, ew2, ew3, dw1, dw2, dw3, zpre,
                                              w1t, w2t, w3t, d1t, d2t, d3t, G);
    fused_k<<<512, blk, 0, stream>>>(xb, w1t, eb1, w2t, eb2, w3t, eb3,
                                     d1t, db1, d2t, db2, d3t, db3, G, eps, part);
    fin_k<<<1, 256, 0, stream>>>(part, out);
}

// Round 10
// 141.400 us; speedup vs baseline: 1.6582x; 1.1402x over previous
//
#include <hip/hip_runtime.h>
#include <hip/hip_bf16.h>
#include <math.h>

#define BB 8192
#define XD 784
#define ZD 10
#define KK 2000
#define HH 300

typedef short short8 __attribute__((ext_vector_type(8)));
typedef float f32x4 __attribute__((ext_vector_type(4)));

__device__ __forceinline__ float sp_(float x) {
    return fmaxf(x, 0.f) + __logf(1.f + __expf(-fabsf(x)));
}
__device__ __forceinline__ float elu_(float x) { return x > 0.f ? x : __expf(x) - 1.f; }
__device__ __forceinline__ unsigned short bf16_(float v) {
    __hip_bfloat16 h = __float2bfloat16(v);
    return __builtin_bit_cast(unsigned short, h);
}
__device__ __forceinline__ float b2f_(unsigned short u) {
    return __builtin_bit_cast(float, (unsigned int)u << 16);
}
// fragment-major write of element (row<32, k) into 2-rowgroup buffer, KS=2
__device__ __forceinline__ void fbw(unsigned short* fb, int row, int k, unsigned short v) {
    fb[(((row >> 4) * 2 + (k >> 5)) * 64 + (row & 15) + (((k >> 3) & 3) << 4)) * 8 + (k & 7)] = v;
}

// Load one wave's B fragments (32 cols x 64 k) for step q directly to VGPRs.
template<int KP, int KI>
__device__ __forceinline__ void ldB(const unsigned short* __restrict__ bbase,
                                    int q, short8 (&f)[2][2]) {
    const int ki = q % KI, ni = q / KI;
    const unsigned short* p = bbase + (size_t)ni * (128 * KP) + ki * 64;
    f[0][0] = *reinterpret_cast<const short8*>(p);
    f[0][1] = *reinterpret_cast<const short8*>(p + 32);
    f[1][0] = *reinterpret_cast<const short8*>(p + 16 * KP);
    f[1][1] = *reinterpret_cast<const short8*>(p + 16 * KP + 32);
}

// ---------------------------------------------------------------------------
// One fused layer on a 32-row slab: C[32][NI*128] = A[32][KP] @ Wt[.][KP]^T
// 4 waves, no intra-layer barriers. Wave w owns cols {n0 + w*32 ..+31}; each
// wave computes ALL 32 rows (2 rowgroups) -> 8 MFMA per 4 B-loads.
// B: global->VGPR, 3-buffer ring, effective prefetch depth 2 (~2 steps).
// A: LDS fragment-major (KS=KP/32 slices per rowgroup).
// LMODE 0: bf16 elu -> actout (STORE GUARDED c<320 — r9 bug was missing it).
// LMODE 1: fp32 c3L (c<20).
// LMODE 2: per-row sum(x*logit - softplus(logit)), x from LDS xs -> redL.
// LMODE 3: per-row online logsumexp (c_k folded in B cols 20/21) -> redM/S.
// ---------------------------------------------------------------------------
template<int LMODE, int KP, int KI, int NI>
__device__ __forceinline__ void layer(
    const int tid,
    const unsigned short* __restrict__ xs,     // LDS x stage (LMODE 2)
    const unsigned short* __restrict__ actin,  // LDS activations
    const unsigned short* __restrict__ Wt,
    const float* __restrict__ bL,
    unsigned short* __restrict__ actout,
    float* __restrict__ c3L, float* __restrict__ redL,
    float* __restrict__ redM, float* __restrict__ redS)
{
    const int w = tid >> 6, l = tid & 63;
    const int cl = l & 15, hi = l >> 4, g4 = hi << 2;
    constexpr int KS = KP / 32;
    constexpr int NQ = KI * NI;
    const unsigned short* bbase = Wt + (size_t)(w * 32 + cl) * KP + hi * 8;

    f32x4 acc[2][2];
    #pragma unroll
    for (int i = 0; i < 2; ++i)
        #pragma unroll
        for (int j = 0; j < 2; ++j) acc[i][j] = (f32x4){0.f, 0.f, 0.f, 0.f};
    float rA[2][4], rB[2][4];
    #pragma unroll
    for (int i = 0; i < 2; ++i)
        #pragma unroll
        for (int r = 0; r < 4; ++r) { rA[i][r] = (LMODE == 3) ? -1e30f : 0.f; rB[i][r] = 0.f; }

    auto step = [&](int q, short8 (&bf)[2][2]) {
        const int cki = q % KI;
        short8 a[2][2];
        #pragma unroll
        for (int rg = 0; rg < 2; ++rg)
            #pragma unroll
            for (int s = 0; s < 2; ++s)
                a[rg][s] = *reinterpret_cast<const short8*>(
                    actin + ((rg * KS + cki * 2 + s) * 64 + l) * 8);
        #pragma unroll
        for (int rg = 0; rg < 2; ++rg)
            #pragma unroll
            for (int cf = 0; cf < 2; ++cf) {
                acc[rg][cf] = __builtin_amdgcn_mfma_f32_16x16x32_bf16(a[rg][0], bf[cf][0], acc[rg][cf], 0, 0, 0);
                acc[rg][cf] = __builtin_amdgcn_mfma_f32_16x16x32_bf16(a[rg][1], bf[cf][1], acc[rg][cf], 0, 0, 0);
            }
        if (cki == KI - 1) {
            const int n0 = (q / KI) * 128;
            if constexpr (LMODE == 0) {
                #pragma unroll
                for (int rg = 0; rg < 2; ++rg)
                    #pragma unroll
                    for (int cf = 0; cf < 2; ++cf) {
                        const int c = n0 + w * 32 + cf * 16 + cl;
                        const float bb = (c < HH) ? bL[c] : 0.f;
                        #pragma unroll
                        for (int rr = 0; rr < 4; ++rr) {
                            float o = (c < HH) ? elu_(acc[rg][cf][rr] + bb) : 0.f;
                            if (c < 320)
                                actout[((rg * 10 + (c >> 5)) * 64 + (g4 + rr) + (((c >> 3) & 3) << 4)) * 8 + (c & 7)] = bf16_(o);
                        }
                    }
            } else if constexpr (LMODE == 1) {
                #pragma unroll
                for (int rg = 0; rg < 2; ++rg)
                    #pragma unroll
                    for (int cf = 0; cf < 2; ++cf) {
                        const int c = w * 32 + cf * 16 + cl;
                        if (c < 20) {
                            #pragma unroll
                            for (int rr = 0; rr < 4; ++rr)
                                c3L[(rg * 16 + g4 + rr) * 24 + c] = acc[rg][cf][rr] + bL[c];
                        }
                    }
            } else if constexpr (LMODE == 2) {
                #pragma unroll
                for (int rg = 0; rg < 2; ++rg)
                    #pragma unroll
                    for (int rr = 0; rr < 4; ++rr) {
                        float s2 = 0.f;
                        #pragma unroll
                        for (int cf = 0; cf < 2; ++cf) {
                            const int c = n0 + w * 32 + cf * 16 + cl;
                            if (c < XD) {
                                float lv = acc[rg][cf][rr] + bL[c];
                                float xv = b2f_(xs[((rg * 26 + (c >> 5)) * 64 + (g4 + rr) + (((c >> 3) & 3) << 4)) * 8 + (c & 7)]);
                                s2 += xv * lv - sp_(lv);
                            }
                        }
                        s2 += __shfl_xor(s2, 1); s2 += __shfl_xor(s2, 2);
                        s2 += __shfl_xor(s2, 4); s2 += __shfl_xor(s2, 8);
                        rA[rg][rr] += s2;
                    }
            } else {
                #pragma unroll
                for (int rg = 0; rg < 2; ++rg)
                    #pragma unroll
                    for (int rr = 0; rr < 4; ++rr) {
                        float v0 = acc[rg][0][rr];
                        float v1 = acc[rg][1][rr];
                        float mx = fmaxf(v0, v1);
                        mx = fmaxf(mx, __shfl_xor(mx, 1)); mx = fmaxf(mx, __shfl_xor(mx, 2));
                        mx = fmaxf(mx, __shfl_xor(mx, 4)); mx = fmaxf(mx, __shfl_xor(mx, 8));
                        float s = __expf(v0 - mx) + __expf(v1 - mx);
                        s += __shfl_xor(s, 1); s += __shfl_xor(s, 2);
                        s += __shfl_xor(s, 4); s += __shfl_xor(s, 8);
                        if (mx > rA[rg][rr]) { rB[rg][rr] = rB[rg][rr] * __expf(rA[rg][rr] - mx) + s; rA[rg][rr] = mx; }
                        else                 { rB[rg][rr] += s * __expf(mx - rA[rg][rr]); }
                    }
            }
            #pragma unroll
            for (int i = 0; i < 2; ++i)
                #pragma unroll
                for (int j = 0; j < 2; ++j) acc[i][j] = (f32x4){0.f, 0.f, 0.f, 0.f};
        }
    };

    short8 b0[2][2], b1[2][2], b2[2][2];
    ldB<KP, KI>(bbase, 0, b0);
    ldB<KP, KI>(bbase, 1, b1);
    int q = 0;
    #pragma unroll 1
    for (; q + 3 <= NQ; q += 3) {
        ldB<KP, KI>(bbase, q + 2, b2);
        step(q, b0);
        if (q + 3 < NQ) ldB<KP, KI>(bbase, q + 3, b0);
        step(q + 1, b1);
        if (q + 4 < NQ) ldB<KP, KI>(bbase, q + 4, b1);
        step(q + 2, b2);
    }
    if (q < NQ)     step(q, b0);
    if (q + 1 < NQ) step(q + 1, b1);

    if (LMODE == 2 && cl == 0) {
        #pragma unroll
        for (int rg = 0; rg < 2; ++rg)
            #pragma unroll
            for (int rr = 0; rr < 4; ++rr)
                redL[(rg * 16 + g4 + rr) * 4 + w] = rA[rg][rr];
    }
    if (LMODE == 3 && cl == 0) {
        #pragma unroll
        for (int rg = 0; rg < 2; ++rg)
            #pragma unroll
            for (int rr = 0; rr < 4; ++rr) {
                redM[(rg * 16 + g4 + rr) * 4 + w] = rA[rg][rr];
                redS[(rg * 16 + g4 + rr) * 4 + w] = rB[rg][rr];
            }
    }
}

__global__ __launch_bounds__(256, 1)
void fused_k(const float* __restrict__ xg,
             const unsigned short* __restrict__ w1t, const float* __restrict__ eb1,
             const unsigned short* __restrict__ w2t, const float* __restrict__ eb2,
             const unsigned short* __restrict__ w3t, const float* __restrict__ eb3,
             const unsigned short* __restrict__ d1t, const float* __restrict__ db1,
             const unsigned short* __restrict__ d2t, const float* __restrict__ db2,
             const unsigned short* __restrict__ d3t, const float* __restrict__ db3,
             const unsigned short* __restrict__ G,
             const float* __restrict__ eps, float* __restrict__ part)
{
    __shared__ __align__(16) unsigned short xs[26624];    // 32x832 bf16, frag-major
    __shared__ __align__(16) unsigned short actP[10240];  // 32x320
    __shared__ __align__(16) unsigned short actQ[10240];
    __shared__ __align__(16) unsigned short fbL[2048];    // 32x64
    __shared__ float biasF[896];
    __shared__ float c3L[768];
    __shared__ float redM[128], redS[128], redL[128], lqzL[32];

    const int tid = threadIdx.x;
    const int m0 = blockIdx.x * 32;

    // stage x (fp32 -> bf16, fragment-major) + zero fb + load eb1
    #pragma unroll 1
    for (int c = tid; c < 32 * 104; c += 256) {
        const int row = c / 104, kc = c - row * 104;
        const int k0 = kc * 8;
        short8 v8 = (short8){0, 0, 0, 0, 0, 0, 0, 0};
        if (k0 < XD) {
            const float* src = xg + (size_t)(m0 + row) * XD + k0;
            float4 f0 = *reinterpret_cast<const float4*>(src);
            float4 f1 = *reinterpret_cast<const float4*>(src + 4);
            v8[0] = (short)bf16_(f0.x); v8[1] = (short)bf16_(f0.y);
            v8[2] = (short)bf16_(f0.z); v8[3] = (short)bf16_(f0.w);
            v8[4] = (short)bf16_(f1.x); v8[5] = (short)bf16_(f1.y);
            v8[6] = (short)bf16_(f1.z); v8[7] = (short)bf16_(f1.w);
        }
        const int rg = row >> 4;
        const int lane = (row & 15) + (((k0 >> 3) & 3) << 4);
        *reinterpret_cast<short8*>(&xs[((rg * 26 + (k0 >> 5)) * 64 + lane) * 8]) = v8;
    }
    reinterpret_cast<uint4*>(fbL)[tid] = (uint4){0u, 0u, 0u, 0u};
    for (int i = tid; i < HH; i += 256) biasF[i] = eb1[i];
    __syncthreads();

    layer<0, 832, 13, 3>(tid, xs, xs, w1t, biasF, actP, nullptr, nullptr, nullptr, nullptr);
    __syncthreads();

    for (int i = tid; i < HH; i += 256) biasF[i] = eb2[i];
    __syncthreads();
    layer<0, 320, 5, 3>(tid, xs, actP, w2t, biasF, actQ, nullptr, nullptr, nullptr, nullptr);
    __syncthreads();

    if (tid < 20) biasF[tid] = eb3[tid];
    __syncthreads();
    layer<1, 320, 5, 1>(tid, xs, actQ, w3t, biasF, nullptr, c3L, nullptr, nullptr, nullptr);
    __syncthreads();

    if (tid < 32) {
        float a = 0.f;
        #pragma unroll
        for (int j = 0; j < ZD; ++j) {
            float qm = c3L[tid * 24 + j];
            float qh = c3L[tid * 24 + 10 + j];
            float qv = sp_(qh) + 1e-8f;
            float e  = eps[(size_t)(m0 + tid) * ZD + j];
            float zj = qm + sqrtf(qv) * e;
            fbw(fbL, tid, j,      bf16_(zj * zj));
            fbw(fbL, tid, 10 + j, bf16_(zj));
            float d = zj - qm;
            a += __logf(6.283185307179586f * qv) + d * d / qv;
        }
        fbw(fbL, tid, 20, bf16_(1.f));   // picks up c_k hi/lo from G cols 20/21
        fbw(fbL, tid, 21, bf16_(1.f));
        lqzL[tid] = -0.5f * a;
    }
    __syncthreads();

    for (int i = tid; i < HH; i += 256) biasF[i] = db1[i];
    __syncthreads();
    layer<0, 64, 1, 3>(tid, xs, fbL, d1t, biasF, actP, nullptr, nullptr, nullptr, nullptr);
    __syncthreads();

    for (int i = tid; i < HH; i += 256) biasF[i] = db2[i];
    __syncthreads();
    layer<0, 320, 5, 3>(tid, xs, actP, d2t, biasF, actQ, nullptr, nullptr, nullptr, nullptr);
    __syncthreads();

    for (int i = tid; i < XD; i += 256) biasF[i] = db3[i];
    __syncthreads();
    layer<2, 320, 5, 7>(tid, xs, actQ, d3t, biasF, nullptr, nullptr, redL, nullptr, nullptr);
    __syncthreads();

    layer<3, 64, 1, 16>(tid, xs, fbL, G, nullptr, nullptr, nullptr, nullptr, redM, redS);
    __syncthreads();

    if (tid < 32) {
        float M0 = redM[tid * 4], M1 = redM[tid * 4 + 1];
        float M2 = redM[tid * 4 + 2], M3 = redM[tid * 4 + 3];
        float M = fmaxf(fmaxf(M0, M1), fmaxf(M2, M3));
        float S = redS[tid * 4] * __expf(M0 - M) + redS[tid * 4 + 1] * __expf(M1 - M)
                + redS[tid * 4 + 2] * __expf(M2 - M) + redS[tid * 4 + 3] * __expf(M3 - M);
        float lpz = M + __logf(S) - 7.6009024595420824f;  // log(2000)
        float lpx = redL[tid * 4] + redL[tid * 4 + 1] + redL[tid * 4 + 2] + redL[tid * 4 + 3];
        float kl = lqzL[tid] - lpz;
        float ne = kl - lpx, re = -lpx;
        #pragma unroll
        for (int d = 1; d <= 16; d <<= 1) {
            ne += __shfl_xor(ne, d); kl += __shfl_xor(kl, d); re += __shfl_xor(re, d);
        }
        if (tid == 0) {
            part[blockIdx.x * 3 + 0] = ne;
            part[blockIdx.x * 3 + 1] = kl;
            part[blockIdx.x * 3 + 2] = re;
        }
    }
}

// weight transposes/pads + GMM coef matrix (c_k folded as bf16 hi/lo cols)
__global__ __launch_bounds__(256)
void prep_k(const float* __restrict__ ew1, const float* __restrict__ ew2,
            const float* __restrict__ ew3, const float* __restrict__ dw1,
            const float* __restrict__ dw2, const float* __restrict__ dw3,
            const float* __restrict__ zpre,
            unsigned short* __restrict__ w1t, unsigned short* __restrict__ w2t,
            unsigned short* __restrict__ w3t, unsigned short* __restrict__ d1t,
            unsigned short* __restrict__ d2t, unsigned short* __restrict__ d3t,
            unsigned short* __restrict__ G)
{
    const int idx = blockIdx.x * 256 + threadIdx.x;
    const int y = blockIdx.y;
    if (y == 0) {
        if (idx >= 384 * 832) return;
        int n = idx / 832, k = idx - n * 832;
        w1t[idx] = bf16_((n < HH && k < XD) ? ew1[(size_t)k * HH + n] : 0.f);
    } else if (y == 1) {
        if (idx >= 384 * 320) return;
        int n = idx / 320, k = idx - n * 320;
        w2t[idx] = bf16_((n < HH && k < HH) ? ew2[(size_t)k * HH + n] : 0.f);
    } else if (y == 2) {
        if (idx >= 128 * 320) return;
        int n = idx / 320, k = idx - n * 320;
        w3t[idx] = bf16_((n < 2 * ZD && k < HH) ? ew3[(size_t)k * 2 * ZD + n] : 0.f);
    } else if (y == 3) {   // d1t [384][64]; dw1 rows at k=10..19 (fb layout: z at 10..19)
        if (idx >= 384 * 64) return;
        int n = idx / 64, k = idx - n * 64;
        float v = (n < HH && k >= 10 && k < 20) ? dw1[(size_t)(k - 10) * HH + n] : 0.f;
        d1t[idx] = bf16_(v);
    } else if (y == 4) {
        if (idx >= 384 * 320) return;
        int n = idx / 320, k = idx - n * 320;
        d2t[idx] = bf16_((n < HH && k < HH) ? dw2[(size_t)k * HH + n] : 0.f);
    } else if (y == 5) {
        if (idx >= 896 * 320) return;
        int n = idx / 320, k = idx - n * 320;
        d3t[idx] = bf16_((n < XD && k < HH) ? dw3[(size_t)k * XD + n] : 0.f);
    } else {
        if (idx >= 2048) return;
        int k = idx;
        if (k < KK) {
            float csum = 0.f;
            #pragma unroll
            for (int j = 0; j < ZD; ++j) {
                float m = zpre[k * ZD + j];
                float h = zpre[(KK + k) * ZD + j];
                float v = sp_(h) + 1e-8f;
                G[k * 64 + j] = bf16_(-0.5f / v);
                G[k * 64 + 10 + j] = bf16_(m / v);
                csum += __logf(6.283185307179586f * v) + m * m / v;
            }
            float ck = -0.5f * csum;
            unsigned short hic = bf16_(ck);
            G[k * 64 + 20] = hic;
            G[k * 64 + 21] = bf16_(ck - b2f_(hic));
            #pragma unroll
            for (int j = 22; j < 64; ++j) G[k * 64 + j] = 0;
        } else {
            #pragma unroll
            for (int j = 0; j < 20; ++j) G[k * 64 + j] = 0;
            G[k * 64 + 20] = bf16_(-1e30f);
            G[k * 64 + 21] = 0;
            #pragma unroll
            for (int j = 22; j < 64; ++j) G[k * 64 + j] = 0;
        }
    }
}

__global__ void fin_k(const float* __restrict__ part, float* __restrict__ out)
{
    int c = threadIdx.x >> 6, l = threadIdx.x & 63;
    if (c < 3) {
        float s = 0.f;
        for (int i = l; i < 256; i += 64) s += part[i * 3 + c];
        #pragma unroll
        for (int d = 1; d < 64; d <<= 1) s += __shfl_xor(s, d);
        if (l == 0) out[c] = s / (float)BB;
    }
}

extern "C" void kernel_launch(void* const* d_in, const int* in_sizes, int n_in,
                              void* d_out, int out_size, void* d_ws, size_t ws_size,
                              hipStream_t stream)
{
    const float* x    = (const float*)d_in[0];
    const float* eps  = (const float*)d_in[1];
    const float* zpre = (const float*)d_in[2];
    const float* ew1  = (const float*)d_in[3];
    const float* eb1  = (const float*)d_in[4];
    const float* ew2  = (const float*)d_in[5];
    const float* eb2  = (const float*)d_in[6];
    const float* ew3  = (const float*)d_in[7];
    const float* eb3  = (const float*)d_in[8];
    const float* dw1  = (const float*)d_in[9];
    const float* db1  = (const float*)d_in[10];
    const float* dw2  = (const float*)d_in[11];
    const float* db2  = (const float*)d_in[12];
    const float* dw3  = (const float*)d_in[13];
    const float* db3  = (const float*)d_in[14];
    float* out = (float*)d_out;

    float* ws   = (float*)d_ws;
    float* part = ws;                        // 256*3
    unsigned short* ub = (unsigned short*)(part + 768);
    unsigned short* w1t = ub; ub += 384 * 832;
    unsigned short* w2t = ub; ub += 384 * 320;
    unsigned short* w3t = ub; ub += 128 * 320;
    unsigned short* d1t = ub; ub += 384 * 64;
    unsigned short* d2t = ub; ub += 384 * 320;
    unsigned short* d3t = ub; ub += 896 * 320;
    unsigned short* G   = ub; ub += 2048 * 64;

    dim3 blk(256);
    prep_k<<<dim3(1248, 7), blk, 0, stream>>>(ew1, ew2, ew3, dw1, dw2, dw3, zpre,
                                              w1t, w2t, w3t, d1t, d2t, d3t, G);
    fused_k<<<256, blk, 0, stream>>>(x, w1t, eb1, w2t, eb2, w3t, eb3,
                                     d1t, db1, d2t, db2, d3t, db3, G, eps, part);
    fin_k<<<1, 256, 0, stream>>>(part, out);
}

// Round 11
// 122.233 us; speedup vs baseline: 1.9182x; 1.1568x over previous
//
#include <hip/hip_runtime.h>
#include <hip/hip_bf16.h>
#include <math.h>

#define BB 8192
#define XD 784
#define ZD 10
#define KK 2000
#define HH 300

typedef short short8 __attribute__((ext_vector_type(8)));
typedef float f32x4 __attribute__((ext_vector_type(4)));

__device__ __forceinline__ float sp_(float x) {
    return fmaxf(x, 0.f) + __logf(1.f + __expf(-fabsf(x)));
}
__device__ __forceinline__ float elu_(float x) { return x > 0.f ? x : __expf(x) - 1.f; }
__device__ __forceinline__ unsigned short bf16_(float v) {
    __hip_bfloat16 h = __float2bfloat16(v);
    return __builtin_bit_cast(unsigned short, h);
}
__device__ __forceinline__ float b2f_(unsigned short u) {
    return __builtin_bit_cast(float, (unsigned int)u << 16);
}
// fragment-major write of element (row<32, k) into 2-rowgroup buffer, KS=2
__device__ __forceinline__ void fbw(unsigned short* fb, int row, int k, unsigned short v) {
    fb[(((row >> 4) * 2 + (k >> 5)) * 64 + (row & 15) + (((k >> 3) & 3) << 4)) * 8 + (k & 7)] = v;
}

// ---------------------------------------------------------------------------
// One fused layer on a 32-row slab: C[32][NI*128] = A[32][KP] @ Wt[.][KP]^T
// 8 waves, no intra-layer barriers. Wave w owns cols {n0 + w*16 ..+15} of
// each 128-col n-tile; computes all 32 rows (2 rowgroups) -> 4 MFMA per
// 2 B-loads per step. B: global->VGPR ring of 4 pair-buffers (2 steps each),
// prefetch distance ~6 steps, 12 loads in flight per wave (96/CU).
// Division-free: load pointer walks +64/step, +127*KP at ni-wrap; compute
// state (cki, n0) advanced per step. Benign over-reads (<=6 steps) land in
// ws slack after the weight buffers.
// A: LDS fragment-major (KS=KP/32 slices per rowgroup).
// LMODE 0: bf16 elu -> actout (guard c<320). LMODE 1: fp32 c3L (c<20).
// LMODE 2: per-row sum(x*logit - softplus(logit)), x from LDS xs -> redL.
// LMODE 3: per-row online logsumexp (c_k folded in B cols 20/21) -> redM/S.
// ---------------------------------------------------------------------------
template<int LMODE, int KP, int KI, int NI>
__device__ __forceinline__ void layer8(
    const int tid,
    const unsigned short* __restrict__ xs,
    const unsigned short* __restrict__ actin,
    const unsigned short* __restrict__ Wt,
    const float* __restrict__ bL,
    unsigned short* __restrict__ actout,
    float* __restrict__ c3L, float* __restrict__ redL,
    float* __restrict__ redM, float* __restrict__ redS)
{
    const int w = tid >> 6, l = tid & 63;
    const int cl = l & 15, hi = l >> 4, g4 = hi << 2;
    constexpr int KS = KP / 32;
    constexpr int NQ = KI * NI;

    const unsigned short* pL = Wt + (size_t)(w * 16 + cl) * KP + hi * 8;
    int kiL = 0;
    int ckiC = 0, n0C = 0;

    f32x4 acc[2];
    acc[0] = (f32x4){0.f, 0.f, 0.f, 0.f};
    acc[1] = (f32x4){0.f, 0.f, 0.f, 0.f};
    float rA[2][4], rB[2][4];
    #pragma unroll
    for (int i = 0; i < 2; ++i)
        #pragma unroll
        for (int r = 0; r < 4; ++r) { rA[i][r] = (LMODE == 3) ? -1e30f : 0.f; rB[i][r] = 0.f; }

    auto advL = [&]() {
        pL += 64;
        if (++kiL == KI) { kiL = 0; pL += (size_t)127 * KP; }
    };
    auto ldB2 = [&](short8 (&P)[4]) {
        P[0] = *reinterpret_cast<const short8*>(pL);
        P[1] = *reinterpret_cast<const short8*>(pL + 32);
        advL();
        P[2] = *reinterpret_cast<const short8*>(pL);
        P[3] = *reinterpret_cast<const short8*>(pL + 32);
        advL();
    };

    auto step = [&](short8 f0, short8 f1) {
        short8 a00 = *reinterpret_cast<const short8*>(actin + ((0 * KS + ckiC * 2 + 0) * 64 + l) * 8);
        short8 a01 = *reinterpret_cast<const short8*>(actin + ((0 * KS + ckiC * 2 + 1) * 64 + l) * 8);
        short8 a10 = *reinterpret_cast<const short8*>(actin + ((1 * KS + ckiC * 2 + 0) * 64 + l) * 8);
        short8 a11 = *reinterpret_cast<const short8*>(actin + ((1 * KS + ckiC * 2 + 1) * 64 + l) * 8);
        acc[0] = __builtin_amdgcn_mfma_f32_16x16x32_bf16(a00, f0, acc[0], 0, 0, 0);
        acc[0] = __builtin_amdgcn_mfma_f32_16x16x32_bf16(a01, f1, acc[0], 0, 0, 0);
        acc[1] = __builtin_amdgcn_mfma_f32_16x16x32_bf16(a10, f0, acc[1], 0, 0, 0);
        acc[1] = __builtin_amdgcn_mfma_f32_16x16x32_bf16(a11, f1, acc[1], 0, 0, 0);
        if (ckiC == KI - 1) {
            if constexpr (LMODE == 0) {
                const int c = n0C + w * 16 + cl;
                const float bb = (c < HH) ? bL[c] : 0.f;
                #pragma unroll
                for (int rg = 0; rg < 2; ++rg)
                    #pragma unroll
                    for (int rr = 0; rr < 4; ++rr) {
                        float o = (c < HH) ? elu_(acc[rg][rr] + bb) : 0.f;
                        if (c < 320)
                            actout[((rg * 10 + (c >> 5)) * 64 + (g4 + rr) + (((c >> 3) & 3) << 4)) * 8 + (c & 7)] = bf16_(o);
                    }
            } else if constexpr (LMODE == 1) {
                const int c = w * 16 + cl;
                if (c < 20) {
                    #pragma unroll
                    for (int rg = 0; rg < 2; ++rg)
                        #pragma unroll
                        for (int rr = 0; rr < 4; ++rr)
                            c3L[(rg * 16 + g4 + rr) * 24 + c] = acc[rg][rr] + bL[c];
                }
            } else if constexpr (LMODE == 2) {
                const int c = n0C + w * 16 + cl;
                #pragma unroll
                for (int rg = 0; rg < 2; ++rg)
                    #pragma unroll
                    for (int rr = 0; rr < 4; ++rr) {
                        float s2 = 0.f;
                        if (c < XD) {
                            float lv = acc[rg][rr] + bL[c];
                            float xv = b2f_(xs[((rg * 26 + (c >> 5)) * 64 + (g4 + rr) + (((c >> 3) & 3) << 4)) * 8 + (c & 7)]);
                            s2 = xv * lv - sp_(lv);
                        }
                        s2 += __shfl_xor(s2, 1); s2 += __shfl_xor(s2, 2);
                        s2 += __shfl_xor(s2, 4); s2 += __shfl_xor(s2, 8);
                        rA[rg][rr] += s2;
                    }
            } else {
                #pragma unroll
                for (int rg = 0; rg < 2; ++rg)
                    #pragma unroll
                    for (int rr = 0; rr < 4; ++rr) {
                        float v0 = acc[rg][rr];
                        float mx = v0;
                        mx = fmaxf(mx, __shfl_xor(mx, 1)); mx = fmaxf(mx, __shfl_xor(mx, 2));
                        mx = fmaxf(mx, __shfl_xor(mx, 4)); mx = fmaxf(mx, __shfl_xor(mx, 8));
                        float s = __expf(v0 - mx);
                        s += __shfl_xor(s, 1); s += __shfl_xor(s, 2);
                        s += __shfl_xor(s, 4); s += __shfl_xor(s, 8);
                        if (mx > rA[rg][rr]) { rB[rg][rr] = rB[rg][rr] * __expf(rA[rg][rr] - mx) + s; rA[rg][rr] = mx; }
                        else                 { rB[rg][rr] += s * __expf(mx - rA[rg][rr]); }
                    }
            }
            acc[0] = (f32x4){0.f, 0.f, 0.f, 0.f};
            acc[1] = (f32x4){0.f, 0.f, 0.f, 0.f};
        }
        if (++ckiC == KI) { ckiC = 0; n0C += 128; }
    };

    short8 P0[4], P1[4], P2[4], P3[4];
    ldB2(P0); ldB2(P1); ldB2(P2);     // steps 0-5 in flight
    int q = 0;
    #pragma unroll 1
    for (; q + 8 <= NQ; q += 8) {
        ldB2(P3);
        step(P0[0], P0[1]); step(P0[2], P0[3]);
        ldB2(P0);
        step(P1[0], P1[1]); step(P1[2], P1[3]);
        ldB2(P1);
        step(P2[0], P2[1]); step(P2[2], P2[3]);
        ldB2(P2);
        step(P3[0], P3[1]); step(P3[2], P3[3]);
    }
    constexpr int TAIL = NQ % 8;
    if constexpr (TAIL >= 7) ldB2(P3);
    if constexpr (TAIL >= 1) step(P0[0], P0[1]);
    if constexpr (TAIL >= 2) step(P0[2], P0[3]);
    if constexpr (TAIL >= 3) step(P1[0], P1[1]);
    if constexpr (TAIL >= 4) step(P1[2], P1[3]);
    if constexpr (TAIL >= 5) step(P2[0], P2[1]);
    if constexpr (TAIL >= 6) step(P2[2], P2[3]);
    if constexpr (TAIL >= 7) step(P3[0], P3[1]);

    if (LMODE == 2 && cl == 0) {
        #pragma unroll
        for (int rg = 0; rg < 2; ++rg)
            #pragma unroll
            for (int rr = 0; rr < 4; ++rr)
                redL[(rg * 16 + g4 + rr) * 8 + w] = rA[rg][rr];
    }
    if (LMODE == 3 && cl == 0) {
        #pragma unroll
        for (int rg = 0; rg < 2; ++rg)
            #pragma unroll
            for (int rr = 0; rr < 4; ++rr) {
                redM[(rg * 16 + g4 + rr) * 8 + w] = rA[rg][rr];
                redS[(rg * 16 + g4 + rr) * 8 + w] = rB[rg][rr];
            }
    }
}

__global__ __launch_bounds__(512, 2)
void fused_k(const float* __restrict__ xg,
             const unsigned short* __restrict__ w1t, const float* __restrict__ eb1,
             const unsigned short* __restrict__ w2t, const float* __restrict__ eb2,
             const unsigned short* __restrict__ w3t, const float* __restrict__ eb3,
             const unsigned short* __restrict__ d1t, const float* __restrict__ db1,
             const unsigned short* __restrict__ d2t, const float* __restrict__ db2,
             const unsigned short* __restrict__ d3t, const float* __restrict__ db3,
             const unsigned short* __restrict__ G,
             const float* __restrict__ eps, float* __restrict__ part)
{
    __shared__ __align__(16) unsigned short xs[26624];    // 32x832 bf16, frag-major
    __shared__ __align__(16) unsigned short actP[10240];  // 32x320
    __shared__ __align__(16) unsigned short actQ[10240];
    __shared__ __align__(16) unsigned short fbL[2048];    // 32x64
    __shared__ float biasF[896];
    __shared__ float c3L[768];
    __shared__ float redM[256], redS[256], redL[256], lqzL[32];

    const int tid = threadIdx.x;
    const int m0 = blockIdx.x * 32;

    // stage x (fp32 -> bf16, fragment-major) + zero fb + load eb1
    #pragma unroll 1
    for (int c = tid; c < 32 * 104; c += 512) {
        const int row = c / 104, kc = c - row * 104;
        const int k0 = kc * 8;
        short8 v8 = (short8){0, 0, 0, 0, 0, 0, 0, 0};
        if (k0 < XD) {
            const float* src = xg + (size_t)(m0 + row) * XD + k0;
            float4 f0 = *reinterpret_cast<const float4*>(src);
            float4 f1 = *reinterpret_cast<const float4*>(src + 4);
            v8[0] = (short)bf16_(f0.x); v8[1] = (short)bf16_(f0.y);
            v8[2] = (short)bf16_(f0.z); v8[3] = (short)bf16_(f0.w);
            v8[4] = (short)bf16_(f1.x); v8[5] = (short)bf16_(f1.y);
            v8[6] = (short)bf16_(f1.z); v8[7] = (short)bf16_(f1.w);
        }
        const int rg = row >> 4;
        const int lane = (row & 15) + ((kc & 3) << 4);
        *reinterpret_cast<short8*>(&xs[((rg * 26 + (kc >> 2)) * 64 + lane) * 8]) = v8;
    }
    if (tid < 128) reinterpret_cast<uint4*>(fbL)[tid] = (uint4){0u, 0u, 0u, 0u};
    for (int i = tid; i < HH; i += 512) biasF[i] = eb1[i];
    __syncthreads();

    layer8<0, 832, 13, 3>(tid, xs, xs, w1t, biasF, actP, nullptr, nullptr, nullptr, nullptr);
    __syncthreads();

    for (int i = tid; i < HH; i += 512) biasF[i] = eb2[i];
    __syncthreads();
    layer8<0, 320, 5, 3>(tid, xs, actP, w2t, biasF, actQ, nullptr, nullptr, nullptr, nullptr);
    __syncthreads();

    if (tid < 20) biasF[tid] = eb3[tid];
    __syncthreads();
    layer8<1, 320, 5, 1>(tid, xs, actQ, w3t, biasF, nullptr, c3L, nullptr, nullptr, nullptr);
    __syncthreads();

    if (tid < 32) {
        float a = 0.f;
        #pragma unroll
        for (int j = 0; j < ZD; ++j) {
            float qm = c3L[tid * 24 + j];
            float qh = c3L[tid * 24 + 10 + j];
            float qv = sp_(qh) + 1e-8f;
            float e  = eps[(size_t)(m0 + tid) * ZD + j];
            float zj = qm + sqrtf(qv) * e;
            fbw(fbL, tid, j,      bf16_(zj * zj));
            fbw(fbL, tid, 10 + j, bf16_(zj));
            float d = zj - qm;
            a += __logf(6.283185307179586f * qv) + d * d / qv;
        }
        fbw(fbL, tid, 20, bf16_(1.f));   // picks up c_k hi/lo from G cols 20/21
        fbw(fbL, tid, 21, bf16_(1.f));
        lqzL[tid] = -0.5f * a;
    }
    __syncthreads();

    for (int i = tid; i < HH; i += 512) biasF[i] = db1[i];
    __syncthreads();
    layer8<0, 64, 1, 3>(tid, xs, fbL, d1t, biasF, actP, nullptr, nullptr, nullptr, nullptr);
    __syncthreads();

    for (int i = tid; i < HH; i += 512) biasF[i] = db2[i];
    __syncthreads();
    layer8<0, 320, 5, 3>(tid, xs, actP, d2t, biasF, actQ, nullptr, nullptr, nullptr, nullptr);
    __syncthreads();

    for (int i = tid; i < XD; i += 512) biasF[i] = db3[i];
    __syncthreads();
    layer8<2, 320, 5, 7>(tid, xs, actQ, d3t, biasF, nullptr, nullptr, redL, nullptr, nullptr);
    __syncthreads();

    layer8<3, 64, 1, 16>(tid, xs, fbL, G, nullptr, nullptr, nullptr, nullptr, redM, redS);
    __syncthreads();

    if (tid < 32) {
        float M = -1e30f;
        #pragma unroll
        for (int w8 = 0; w8 < 8; ++w8) M = fmaxf(M, redM[tid * 8 + w8]);
        float S = 0.f;
        #pragma unroll
        for (int w8 = 0; w8 < 8; ++w8) S += redS[tid * 8 + w8] * __expf(redM[tid * 8 + w8] - M);
        float lpz = M + __logf(S) - 7.6009024595420824f;  // log(2000)
        float lpx = 0.f;
        #pragma unroll
        for (int w8 = 0; w8 < 8; ++w8) lpx += redL[tid * 8 + w8];
        float kl = lqzL[tid] - lpz;
        float ne = kl - lpx, re = -lpx;
        #pragma unroll
        for (int d = 1; d <= 16; d <<= 1) {
            ne += __shfl_xor(ne, d); kl += __shfl_xor(kl, d); re += __shfl_xor(re, d);
        }
        if (tid == 0) {
            part[blockIdx.x * 3 + 0] = ne;
            part[blockIdx.x * 3 + 1] = kl;
            part[blockIdx.x * 3 + 2] = re;
        }
    }
}

// weight transposes/pads + GMM coef matrix (c_k folded as bf16 hi/lo cols)
__global__ __launch_bounds__(256)
void prep_k(const float* __restrict__ ew1, const float* __restrict__ ew2,
            const float* __restrict__ ew3, const float* __restrict__ dw1,
            const float* __restrict__ dw2, const float* __restrict__ dw3,
            const float* __restrict__ zpre,
            unsigned short* __restrict__ w1t, unsigned short* __restrict__ w2t,
            unsigned short* __restrict__ w3t, unsigned short* __restrict__ d1t,
            unsigned short* __restrict__ d2t, unsigned short* __restrict__ d3t,
            unsigned short* __restrict__ G)
{
    const int idx = blockIdx.x * 256 + threadIdx.x;
    const int y = blockIdx.y;
    if (y == 0) {
        if (idx >= 384 * 832) return;
        int n = idx / 832, k = idx - n * 832;
        w1t[idx] = bf16_((n < HH && k < XD) ? ew1[(size_t)k * HH + n] : 0.f);
    } else if (y == 1) {
        if (idx >= 384 * 320) return;
        int n = idx / 320, k = idx - n * 320;
        w2t[idx] = bf16_((n < HH && k < HH) ? ew2[(size_t)k * HH + n] : 0.f);
    } else if (y == 2) {
        if (idx >= 128 * 320) return;
        int n = idx / 320, k = idx - n * 320;
        w3t[idx] = bf16_((n < 2 * ZD && k < HH) ? ew3[(size_t)k * 2 * ZD + n] : 0.f);
    } else if (y == 3) {   // d1t [384][64]; dw1 rows at k=10..19 (fb layout: z at 10..19)
        if (idx >= 384 * 64) return;
        int n = idx / 64, k = idx - n * 64;
        float v = (n < HH && k >= 10 && k < 20) ? dw1[(size_t)(k - 10) * HH + n] : 0.f;
        d1t[idx] = bf16_(v);
    } else if (y == 4) {
        if (idx >= 384 * 320) return;
        int n = idx / 320, k = idx - n * 320;
        d2t[idx] = bf16_((n < HH && k < HH) ? dw2[(size_t)k * HH + n] : 0.f);
    } else if (y == 5) {
        if (idx >= 896 * 320) return;
        int n = idx / 320, k = idx - n * 320;
        d3t[idx] = bf16_((n < XD && k < HH) ? dw3[(size_t)k * XD + n] : 0.f);
    } else {
        if (idx >= 2048) return;
        int k = idx;
        if (k < KK) {
            float csum = 0.f;
            #pragma unroll
            for (int j = 0; j < ZD; ++j) {
                float m = zpre[k * ZD + j];
                float h = zpre[(KK + k) * ZD + j];
                float v = sp_(h) + 1e-8f;
                G[k * 64 + j] = bf16_(-0.5f / v);
                G[k * 64 + 10 + j] = bf16_(m / v);
                csum += __logf(6.283185307179586f * v) + m * m / v;
            }
            float ck = -0.5f * csum;
            unsigned short hic = bf16_(ck);
            G[k * 64 + 20] = hic;
            G[k * 64 + 21] = bf16_(ck - b2f_(hic));
            #pragma unroll
            for (int j = 22; j < 64; ++j) G[k * 64 + j] = 0;
        } else {
            #pragma unroll
            for (int j = 0; j < 20; ++j) G[k * 64 + j] = 0;
            G[k * 64 + 20] = bf16_(-1e30f);
            G[k * 64 + 21] = 0;
            #pragma unroll
            for (int j = 22; j < 64; ++j) G[k * 64 + j] = 0;
        }
    }
}

__global__ void fin_k(const float* __restrict__ part, float* __restrict__ out)
{
    int c = threadIdx.x >> 6, l = threadIdx.x & 63;
    if (c < 3) {
        float s = 0.f;
        for (int i = l; i < 256; i += 64) s += part[i * 3 + c];
        #pragma unroll
        for (int d = 1; d < 64; d <<= 1) s += __shfl_xor(s, d);
        if (l == 0) out[c] = s / (float)BB;
    }
}

extern "C" void kernel_launch(void* const* d_in, const int* in_sizes, int n_in,
                              void* d_out, int out_size, void* d_ws, size_t ws_size,
                              hipStream_t stream)
{
    const float* x    = (const float*)d_in[0];
    const float* eps  = (const float*)d_in[1];
    const float* zpre = (const float*)d_in[2];
    const float* ew1  = (const float*)d_in[3];
    const float* eb1  = (const float*)d_in[4];
    const float* ew2  = (const float*)d_in[5];
    const float* eb2  = (const float*)d_in[6];
    const float* ew3  = (const float*)d_in[7];
    const float* eb3  = (const float*)d_in[8];
    const float* dw1  = (const float*)d_in[9];
    const float* db1  = (const float*)d_in[10];
    const float* dw2  = (const float*)d_in[11];
    const float* db2  = (const float*)d_in[12];
    const float* dw3  = (const float*)d_in[13];
    const float* db3  = (const float*)d_in[14];
    float* out = (float*)d_out;

    float* ws   = (float*)d_ws;
    float* part = ws;                        // 256*3
    unsigned short* ub = (unsigned short*)(part + 768);
    unsigned short* w1t = ub; ub += 384 * 832;
    unsigned short* w2t = ub; ub += 384 * 320;
    unsigned short* w3t = ub; ub += 128 * 320;
    unsigned short* d1t = ub; ub += 384 * 64;
    unsigned short* d2t = ub; ub += 384 * 320;
    unsigned short* d3t = ub; ub += 896 * 320;
    unsigned short* G   = ub; ub += 2048 * 64;
    // note: ring prefetch may over-read <=16KB past G; ws is far larger.

    dim3 blk(256);
    prep_k<<<dim3(1248, 7), blk, 0, stream>>>(ew1, ew2, ew3, dw1, dw2, dw3, zpre,
                                              w1t, w2t, w3t, d1t, d2t, d3t, G);
    fused_k<<<256, 512, 0, stream>>>(x, w1t, eb1, w2t, eb2, w3t, eb3,
                                     d1t, db1, d2t, db2, d3t, db3, G, eps, part);
    fin_k<<<1, 256, 0, stream>>>(part, out);
}

// Round 12
// 90.992 us; speedup vs baseline: 2.5768x; 1.3433x over previous
//
#include <hip/hip_runtime.h>
#include <hip/hip_bf16.h>
#include <math.h>

#define BB 8192
#define XD 784
#define ZD 10
#define KK 2000
#define HH 300

typedef short short8 __attribute__((ext_vector_type(8)));
typedef float f32x4 __attribute__((ext_vector_type(4)));

__device__ __forceinline__ float sp_(float x) {
    return fmaxf(x, 0.f) + __logf(1.f + __expf(-fabsf(x)));
}
__device__ __forceinline__ float elu_(float x) { return x > 0.f ? x : __expf(x) - 1.f; }
__device__ __forceinline__ unsigned short bf16_(float v) {
    __hip_bfloat16 h = __float2bfloat16(v);
    return __builtin_bit_cast(unsigned short, h);
}
__device__ __forceinline__ float b2f_(unsigned short u) {
    return __builtin_bit_cast(float, (unsigned int)u << 16);
}
// fragment-major write of element (row<32, k) into 2-rowgroup buffer, KS=2
__device__ __forceinline__ void fbw(unsigned short* fb, int row, int k, unsigned short v) {
    fb[(((row >> 4) * 2 + (k >> 5)) * 64 + (row & 15) + (((k >> 3) & 3) << 4)) * 8 + (k & 7)] = v;
}

// ---------------------------------------------------------------------------
// ki-major layer: C[32][NI*128] = A[32][KP] @ Wt[.][KP]^T, 8 waves, no
// intra-layer barriers, wave w owns cols {ni*128 + w*16..+15}. acc[NI][2]
// lives across the layer; A read once per ki (4 ds_read); B double-buffered
// per ki. FULLY UNROLLED straight-line code; epilogue runs ONCE per layer;
// NO cross-lane ops inside loops.
// LMODE 0: bf16 elu -> actout (guard c<320).
// LMODE 1: fp32 c3L (c<20).
// LMODE 2: per-row sum(x*logit - softplus(logit)); per-lane partials, one
//          cross-lane reduce at end -> redL.
// ---------------------------------------------------------------------------
template<int LMODE, int KP, int KI, int NI>
__device__ __forceinline__ void layerKM(
    const int tid,
    const unsigned short* __restrict__ xs,
    const unsigned short* __restrict__ actin,
    const unsigned short* __restrict__ Wt,
    const float* __restrict__ bL,
    unsigned short* __restrict__ actout,
    float* __restrict__ c3L, float* __restrict__ redL)
{
    const int w = tid >> 6, l = tid & 63;
    const int cl = l & 15, hi = l >> 4, g4 = hi << 2;
    constexpr int KS = KP / 32;
    const unsigned short* bp = Wt + (size_t)(w * 16 + cl) * KP + hi * 8;

    f32x4 acc[NI][2];
    #pragma unroll
    for (int ni = 0; ni < NI; ++ni) {
        acc[ni][0] = (f32x4){0.f, 0.f, 0.f, 0.f};
        acc[ni][1] = (f32x4){0.f, 0.f, 0.f, 0.f};
    }

    short8 Bb[2][NI][2];
    #pragma unroll
    for (int ni = 0; ni < NI; ++ni) {
        Bb[0][ni][0] = *reinterpret_cast<const short8*>(bp + (size_t)ni * 128 * KP);
        Bb[0][ni][1] = *reinterpret_cast<const short8*>(bp + (size_t)ni * 128 * KP + 32);
    }
    #pragma unroll
    for (int ki = 0; ki < KI; ++ki) {
        const int cur = ki & 1, nxt = cur ^ 1;
        if (ki + 1 < KI) {
            #pragma unroll
            for (int ni = 0; ni < NI; ++ni) {
                Bb[nxt][ni][0] = *reinterpret_cast<const short8*>(bp + (ki + 1) * 64 + (size_t)ni * 128 * KP);
                Bb[nxt][ni][1] = *reinterpret_cast<const short8*>(bp + (ki + 1) * 64 + (size_t)ni * 128 * KP + 32);
            }
        }
        short8 a[2][2];
        #pragma unroll
        for (int rg = 0; rg < 2; ++rg)
            #pragma unroll
            for (int s = 0; s < 2; ++s)
                a[rg][s] = *reinterpret_cast<const short8*>(actin + ((rg * KS + ki * 2 + s) * 64 + l) * 8);
        #pragma unroll
        for (int ni = 0; ni < NI; ++ni)
            #pragma unroll
            for (int rg = 0; rg < 2; ++rg) {
                acc[ni][rg] = __builtin_amdgcn_mfma_f32_16x16x32_bf16(a[rg][0], Bb[cur][ni][0], acc[ni][rg], 0, 0, 0);
                acc[ni][rg] = __builtin_amdgcn_mfma_f32_16x16x32_bf16(a[rg][1], Bb[cur][ni][1], acc[ni][rg], 0, 0, 0);
            }
    }

    if constexpr (LMODE == 0) {
        #pragma unroll
        for (int ni = 0; ni < NI; ++ni) {
            const int c = ni * 128 + w * 16 + cl;
            const float bb = (c < HH) ? bL[c] : 0.f;
            #pragma unroll
            for (int rg = 0; rg < 2; ++rg)
                #pragma unroll
                for (int rr = 0; rr < 4; ++rr) {
                    float o = (c < HH) ? elu_(acc[ni][rg][rr] + bb) : 0.f;
                    if (c < 320)
                        actout[((rg * 10 + (c >> 5)) * 64 + (g4 + rr) + (((c >> 3) & 3) << 4)) * 8 + (c & 7)] = bf16_(o);
                }
        }
    } else if constexpr (LMODE == 1) {
        const int c = w * 16 + cl;
        if (c < 20) {
            #pragma unroll
            for (int rg = 0; rg < 2; ++rg)
                #pragma unroll
                for (int rr = 0; rr < 4; ++rr)
                    c3L[(rg * 16 + g4 + rr) * 24 + c] = acc[0][rg][rr] + bL[c];
        }
    } else {
        float rs[2][4] = {{0.f, 0.f, 0.f, 0.f}, {0.f, 0.f, 0.f, 0.f}};
        #pragma unroll
        for (int ni = 0; ni < NI; ++ni) {
            const int c = ni * 128 + w * 16 + cl;
            if (c < XD) {
                const float bb = bL[c];
                #pragma unroll
                for (int rg = 0; rg < 2; ++rg)
                    #pragma unroll
                    for (int rr = 0; rr < 4; ++rr) {
                        float lv = acc[ni][rg][rr] + bb;
                        float xv = b2f_(xs[((rg * 26 + (c >> 5)) * 64 + (g4 + rr) + (((c >> 3) & 3) << 4)) * 8 + (c & 7)]);
                        rs[rg][rr] += xv * lv - sp_(lv);
                    }
            }
        }
        #pragma unroll
        for (int rg = 0; rg < 2; ++rg)
            #pragma unroll
            for (int rr = 0; rr < 4; ++rr) {
                float s = rs[rg][rr];
                s += __shfl_xor(s, 1); s += __shfl_xor(s, 2);
                s += __shfl_xor(s, 4); s += __shfl_xor(s, 8);
                if (cl == 0) redL[(rg * 16 + g4 + rr) * 8 + w] = s;
            }
    }
}

// ---------------------------------------------------------------------------
// KI=1 layers (KP=64, A in regs once). LMODE 0: dec1 (elu store per ni).
// LMODE 3: comp — per-lane ONLINE logsumexp over the ni dimension (no
// cross-lane ops in loop), one pairwise online merge across 16 lanes at end.
// ---------------------------------------------------------------------------
template<int LMODE, int NI>
__device__ __forceinline__ void layerNM(
    const int tid,
    const unsigned short* __restrict__ actin,
    const unsigned short* __restrict__ Wt,
    const float* __restrict__ bL,
    unsigned short* __restrict__ actout,
    float* __restrict__ redM, float* __restrict__ redS)
{
    const int w = tid >> 6, l = tid & 63;
    const int cl = l & 15, hi = l >> 4, g4 = hi << 2;
    const unsigned short* bp = Wt + (size_t)(w * 16 + cl) * 64 + hi * 8;

    short8 a[2][2];
    #pragma unroll
    for (int rg = 0; rg < 2; ++rg)
        #pragma unroll
        for (int s = 0; s < 2; ++s)
            a[rg][s] = *reinterpret_cast<const short8*>(actin + ((rg * 2 + s) * 64 + l) * 8);

    float rA[2][4], rB[2][4];
    #pragma unroll
    for (int rg = 0; rg < 2; ++rg)
        #pragma unroll
        for (int rr = 0; rr < 4; ++rr) { rA[rg][rr] = -1e30f; rB[rg][rr] = 0.f; }

    #pragma unroll
    for (int ni = 0; ni < NI; ++ni) {
        short8 f0 = *reinterpret_cast<const short8*>(bp + (size_t)ni * 128 * 64);
        short8 f1 = *reinterpret_cast<const short8*>(bp + (size_t)ni * 128 * 64 + 32);
        f32x4 acc[2];
        #pragma unroll
        for (int rg = 0; rg < 2; ++rg) {
            acc[rg] = __builtin_amdgcn_mfma_f32_16x16x32_bf16(a[rg][0], f0, (f32x4){0.f, 0.f, 0.f, 0.f}, 0, 0, 0);
            acc[rg] = __builtin_amdgcn_mfma_f32_16x16x32_bf16(a[rg][1], f1, acc[rg], 0, 0, 0);
        }
        if constexpr (LMODE == 0) {
            const int c = ni * 128 + w * 16 + cl;
            const float bb = (c < HH) ? bL[c] : 0.f;
            #pragma unroll
            for (int rg = 0; rg < 2; ++rg)
                #pragma unroll
                for (int rr = 0; rr < 4; ++rr) {
                    float o = (c < HH) ? elu_(acc[rg][rr] + bb) : 0.f;
                    if (c < 320)
                        actout[((rg * 10 + (c >> 5)) * 64 + (g4 + rr) + (((c >> 3) & 3) << 4)) * 8 + (c & 7)] = bf16_(o);
                }
        } else {
            #pragma unroll
            for (int rg = 0; rg < 2; ++rg)
                #pragma unroll
                for (int rr = 0; rr < 4; ++rr) {
                    float v = acc[rg][rr];
                    float mx = fmaxf(v, rA[rg][rr]);
                    rB[rg][rr] = rB[rg][rr] * __expf(rA[rg][rr] - mx) + __expf(v - mx);
                    rA[rg][rr] = mx;
                }
        }
    }
    if constexpr (LMODE == 3) {
        #pragma unroll
        for (int d = 1; d <= 8; d <<= 1)
            #pragma unroll
            for (int rg = 0; rg < 2; ++rg)
                #pragma unroll
                for (int rr = 0; rr < 4; ++rr) {
                    float mo = __shfl_xor(rA[rg][rr], d);
                    float so = __shfl_xor(rB[rg][rr], d);
                    float M = fmaxf(rA[rg][rr], mo);
                    rB[rg][rr] = rB[rg][rr] * __expf(rA[rg][rr] - M) + so * __expf(mo - M);
                    rA[rg][rr] = M;
                }
        if (cl == 0) {
            #pragma unroll
            for (int rg = 0; rg < 2; ++rg)
                #pragma unroll
                for (int rr = 0; rr < 4; ++rr) {
                    redM[(rg * 16 + g4 + rr) * 8 + w] = rA[rg][rr];
                    redS[(rg * 16 + g4 + rr) * 8 + w] = rB[rg][rr];
                }
        }
    }
}

__global__ __launch_bounds__(512, 2)
void fused_k(const float* __restrict__ xg,
             const unsigned short* __restrict__ w1t, const float* __restrict__ eb1,
             const unsigned short* __restrict__ w2t, const float* __restrict__ eb2,
             const unsigned short* __restrict__ w3t, const float* __restrict__ eb3,
             const unsigned short* __restrict__ d1t, const float* __restrict__ db1,
             const unsigned short* __restrict__ d2t, const float* __restrict__ db2,
             const unsigned short* __restrict__ d3t, const float* __restrict__ db3,
             const unsigned short* __restrict__ G,
             const float* __restrict__ eps, float* __restrict__ part)
{
    __shared__ __align__(16) unsigned short xs[26624];    // 32x832 bf16, frag-major
    __shared__ __align__(16) unsigned short actP[10240];  // 32x320
    __shared__ __align__(16) unsigned short actQ[10240];
    __shared__ __align__(16) unsigned short fbL[2048];    // 32x64
    __shared__ float biasF[896];
    __shared__ float c3L[768];
    __shared__ float redM[256], redS[256], redL[256], lqzL[32];

    const int tid = threadIdx.x;
    const int m0 = blockIdx.x * 32;

    // stage x (fp32 -> bf16, fragment-major) + zero fb + load eb1
    #pragma unroll 1
    for (int c = tid; c < 32 * 104; c += 512) {
        const int row = c / 104, kc = c - row * 104;
        const int k0 = kc * 8;
        short8 v8 = (short8){0, 0, 0, 0, 0, 0, 0, 0};
        if (k0 < XD) {
            const float* src = xg + (size_t)(m0 + row) * XD + k0;
            float4 f0 = *reinterpret_cast<const float4*>(src);
            float4 f1 = *reinterpret_cast<const float4*>(src + 4);
            v8[0] = (short)bf16_(f0.x); v8[1] = (short)bf16_(f0.y);
            v8[2] = (short)bf16_(f0.z); v8[3] = (short)bf16_(f0.w);
            v8[4] = (short)bf16_(f1.x); v8[5] = (short)bf16_(f1.y);
            v8[6] = (short)bf16_(f1.z); v8[7] = (short)bf16_(f1.w);
        }
        const int rg = row >> 4;
        const int lane = (row & 15) + ((kc & 3) << 4);
        *reinterpret_cast<short8*>(&xs[((rg * 26 + (kc >> 2)) * 64 + lane) * 8]) = v8;
    }
    if (tid < 128) reinterpret_cast<uint4*>(fbL)[tid] = (uint4){0u, 0u, 0u, 0u};
    for (int i = tid; i < HH; i += 512) biasF[i] = eb1[i];
    __syncthreads();

    layerKM<0, 832, 13, 3>(tid, xs, xs, w1t, biasF, actP, nullptr, nullptr);
    __syncthreads();

    for (int i = tid; i < HH; i += 512) biasF[i] = eb2[i];
    __syncthreads();
    layerKM<0, 320, 5, 3>(tid, xs, actP, w2t, biasF, actQ, nullptr, nullptr);
    __syncthreads();

    if (tid < 20) biasF[tid] = eb3[tid];
    __syncthreads();
    layerKM<1, 320, 5, 1>(tid, xs, actQ, w3t, biasF, nullptr, c3L, nullptr);
    __syncthreads();

    if (tid < 32) {
        float a = 0.f;
        #pragma unroll
        for (int j = 0; j < ZD; ++j) {
            float qm = c3L[tid * 24 + j];
            float qh = c3L[tid * 24 + 10 + j];
            float qv = sp_(qh) + 1e-8f;
            float e  = eps[(size_t)(m0 + tid) * ZD + j];
            float zj = qm + sqrtf(qv) * e;
            fbw(fbL, tid, j,      bf16_(zj * zj));
            fbw(fbL, tid, 10 + j, bf16_(zj));
            float d = zj - qm;
            a += __logf(6.283185307179586f * qv) + d * d / qv;
        }
        fbw(fbL, tid, 20, bf16_(1.f));   // picks up c_k hi/lo from G cols 20/21
        fbw(fbL, tid, 21, bf16_(1.f));
        lqzL[tid] = -0.5f * a;
    }
    __syncthreads();

    for (int i = tid; i < HH; i += 512) biasF[i] = db1[i];
    __syncthreads();
    layerNM<0, 3>(tid, fbL, d1t, biasF, actP, nullptr, nullptr);
    __syncthreads();

    for (int i = tid; i < HH; i += 512) biasF[i] = db2[i];
    __syncthreads();
    layerKM<0, 320, 5, 3>(tid, xs, actP, d2t, biasF, actQ, nullptr, nullptr);
    __syncthreads();

    for (int i = tid; i < XD; i += 512) biasF[i] = db3[i];
    __syncthreads();
    layerKM<2, 320, 5, 7>(tid, xs, actQ, d3t, biasF, nullptr, nullptr, redL);
    __syncthreads();

    layerNM<3, 16>(tid, fbL, G, nullptr, nullptr, redM, redS);
    __syncthreads();

    if (tid < 32) {
        float M = -1e30f;
        #pragma unroll
        for (int w8 = 0; w8 < 8; ++w8) M = fmaxf(M, redM[tid * 8 + w8]);
        float S = 0.f;
        #pragma unroll
        for (int w8 = 0; w8 < 8; ++w8) S += redS[tid * 8 + w8] * __expf(redM[tid * 8 + w8] - M);
        float lpz = M + __logf(S) - 7.6009024595420824f;  // log(2000)
        float lpx = 0.f;
        #pragma unroll
        for (int w8 = 0; w8 < 8; ++w8) lpx += redL[tid * 8 + w8];
        float kl = lqzL[tid] - lpz;
        float ne = kl - lpx, re = -lpx;
        #pragma unroll
        for (int d = 1; d <= 16; d <<= 1) {
            ne += __shfl_xor(ne, d); kl += __shfl_xor(kl, d); re += __shfl_xor(re, d);
        }
        if (tid == 0) {
            part[blockIdx.x * 3 + 0] = ne;
            part[blockIdx.x * 3 + 1] = kl;
            part[blockIdx.x * 3 + 2] = re;
        }
    }
}

// weight transposes/pads + GMM coef matrix (c_k folded as bf16 hi/lo cols)
__global__ __launch_bounds__(256)
void prep_k(const float* __restrict__ ew1, const float* __restrict__ ew2,
            const float* __restrict__ ew3, const float* __restrict__ dw1,
            const float* __restrict__ dw2, const float* __restrict__ dw3,
            const float* __restrict__ zpre,
            unsigned short* __restrict__ w1t, unsigned short* __restrict__ w2t,
            unsigned short* __restrict__ w3t, unsigned short* __restrict__ d1t,
            unsigned short* __restrict__ d2t, unsigned short* __restrict__ d3t,
            unsigned short* __restrict__ G)
{
    const int idx = blockIdx.x * 256 + threadIdx.x;
    const int y = blockIdx.y;
    if (y == 0) {
        if (idx >= 384 * 832) return;
        int n = idx / 832, k = idx - n * 832;
        w1t[idx] = bf16_((n < HH && k < XD) ? ew1[(size_t)k * HH + n] : 0.f);
    } else if (y == 1) {
        if (idx >= 384 * 320) return;
        int n = idx / 320, k = idx - n * 320;
        w2t[idx] = bf16_((n < HH && k < HH) ? ew2[(size_t)k * HH + n] : 0.f);
    } else if (y == 2) {
        if (idx >= 128 * 320) return;
        int n = idx / 320, k = idx - n * 320;
        w3t[idx] = bf16_((n < 2 * ZD && k < HH) ? ew3[(size_t)k * 2 * ZD + n] : 0.f);
    } else if (y == 3) {   // d1t [384][64]; dw1 rows at k=10..19 (fb layout: z at 10..19)
        if (idx >= 384 * 64) return;
        int n = idx / 64, k = idx - n * 64;
        float v = (n < HH && k >= 10 && k < 20) ? dw1[(size_t)(k - 10) * HH + n] : 0.f;
        d1t[idx] = bf16_(v);
    } else if (y == 4) {
        if (idx >= 384 * 320) return;
        int n = idx / 320, k = idx - n * 320;
        d2t[idx] = bf16_((n < HH && k < HH) ? dw2[(size_t)k * HH + n] : 0.f);
    } else if (y == 5) {
        if (idx >= 896 * 320) return;
        int n = idx / 320, k = idx - n * 320;
        d3t[idx] = bf16_((n < XD && k < HH) ? dw3[(size_t)k * XD + n] : 0.f);
    } else {
        if (idx >= 2048) return;
        int k = idx;
        if (k < KK) {
            float csum = 0.f;
            #pragma unroll
            for (int j = 0; j < ZD; ++j) {
                float m = zpre[k * ZD + j];
                float h = zpre[(KK + k) * ZD + j];
                float v = sp_(h) + 1e-8f;
                G[k * 64 + j] = bf16_(-0.5f / v);
                G[k * 64 + 10 + j] = bf16_(m / v);
                csum += __logf(6.283185307179586f * v) + m * m / v;
            }
            float ck = -0.5f * csum;
            unsigned short hic = bf16_(ck);
            G[k * 64 + 20] = hic;
            G[k * 64 + 21] = bf16_(ck - b2f_(hic));
            #pragma unroll
            for (int j = 22; j < 64; ++j) G[k * 64 + j] = 0;
        } else {
            #pragma unroll
            for (int j = 0; j < 20; ++j) G[k * 64 + j] = 0;
            G[k * 64 + 20] = bf16_(-1e30f);
            G[k * 64 + 21] = 0;
            #pragma unroll
            for (int j = 22; j < 64; ++j) G[k * 64 + j] = 0;
        }
    }
}

__global__ void fin_k(const float* __restrict__ part, float* __restrict__ out)
{
    int c = threadIdx.x >> 6, l = threadIdx.x & 63;
    if (c < 3) {
        float s = 0.f;
        for (int i = l; i < 256; i += 64) s += part[i * 3 + c];
        #pragma unroll
        for (int d = 1; d < 64; d <<= 1) s += __shfl_xor(s, d);
        if (l == 0) out[c] = s / (float)BB;
    }
}

extern "C" void kernel_launch(void* const* d_in, const int* in_sizes, int n_in,
                              void* d_out, int out_size, void* d_ws, size_t ws_size,
                              hipStream_t stream)
{
    const float* x    = (const float*)d_in[0];
    const float* eps  = (const float*)d_in[1];
    const float* zpre = (const float*)d_in[2];
    const float* ew1  = (const float*)d_in[3];
    const float* eb1  = (const float*)d_in[4];
    const float* ew2  = (const float*)d_in[5];
    const float* eb2  = (const float*)d_in[6];
    const float* ew3  = (const float*)d_in[7];
    const float* eb3  = (const float*)d_in[8];
    const float* dw1  = (const float*)d_in[9];
    const float* db1  = (const float*)d_in[10];
    const float* dw2  = (const float*)d_in[11];
    const float* db2  = (const float*)d_in[12];
    const float* dw3  = (const float*)d_in[13];
    const float* db3  = (const float*)d_in[14];
    float* out = (float*)d_out;

    float* ws   = (float*)d_ws;
    float* part = ws;                        // 256*3
    unsigned short* ub = (unsigned short*)(part + 768);
    unsigned short* w1t = ub; ub += 384 * 832;
    unsigned short* w2t = ub; ub += 384 * 320;
    unsigned short* w3t = ub; ub += 128 * 320;
    unsigned short* d1t = ub; ub += 384 * 64;
    unsigned short* d2t = ub; ub += 384 * 320;
    unsigned short* d3t = ub; ub += 896 * 320;
    unsigned short* G   = ub; ub += 2048 * 64;

    dim3 blk(256);
    prep_k<<<dim3(1248, 7), blk, 0, stream>>>(ew1, ew2, ew3, dw1, dw2, dw3, zpre,
                                              w1t, w2t, w3t, d1t, d2t, d3t, G);
    fused_k<<<256, 512, 0, stream>>>(x, w1t, eb1, w2t, eb2, w3t, eb3,
                                     d1t, db1, d2t, db2, d3t, db3, G, eps, part);
    fin_k<<<1, 256, 0, stream>>>(part, out);
}

// Round 14
// 87.775 us; speedup vs baseline: 2.6712x; 1.0366x over previous
//
#include <hip/hip_runtime.h>
#include <hip/hip_bf16.h>
#include <math.h>

#define BB 8192
#define XD 784
#define ZD 10
#define KK 2000
#define HH 300

typedef short short8 __attribute__((ext_vector_type(8)));
typedef float f32x4 __attribute__((ext_vector_type(4)));

__device__ __forceinline__ float sp_(float x) {
    return fmaxf(x, 0.f) + __logf(1.f + __expf(-fabsf(x)));
}
__device__ __forceinline__ float elu_(float x) { return x > 0.f ? x : __expf(x) - 1.f; }
__device__ __forceinline__ unsigned short bf16_(float v) {
    __hip_bfloat16 h = __float2bfloat16(v);
    return __builtin_bit_cast(unsigned short, h);
}
__device__ __forceinline__ float b2f_(unsigned short u) {
    return __builtin_bit_cast(float, (unsigned int)u << 16);
}
__device__ __forceinline__ short8 ld8_(const unsigned short* p) {
    return *reinterpret_cast<const short8*>(p);
}
// fragment-major write of element (row<32, k) into 2-rowgroup buffer, KS=2
__device__ __forceinline__ void fbw(unsigned short* fb, int row, int k, unsigned short v) {
    fb[(((row >> 4) * 2 + (k >> 5)) * 64 + (row & 15) + (((k >> 3) & 3) << 4)) * 8 + (k & 7)] = v;
}

// ---------------------------------------------------------------------------
// ki-major layer (small NI: registers hold B for ALL ni): acc[NI][2] across
// layer, B double-buffered per ki, epilogue once per layer, no cross-lane
// ops in loops. 8 waves, wave w owns cols {ni*128 + w*16..+15}.
// LMODE 0: bf16 elu -> actout (guard c<320). LMODE 1: fp32 c3L (c<20).
// ---------------------------------------------------------------------------
template<int LMODE, int KP, int KI, int NI>
__device__ __forceinline__ void layerKM(
    const int tid,
    const unsigned short* __restrict__ actin,
    const unsigned short* __restrict__ Wt,
    const float* __restrict__ bL,
    unsigned short* __restrict__ actout,
    float* __restrict__ c3L)
{
    const int w = tid >> 6, l = tid & 63;
    const int cl = l & 15, hi = l >> 4, g4 = hi << 2;
    constexpr int KS = KP / 32;
    const unsigned short* bp = Wt + (size_t)(w * 16 + cl) * KP + hi * 8;

    f32x4 acc[NI][2];
    #pragma unroll
    for (int ni = 0; ni < NI; ++ni) {
        acc[ni][0] = (f32x4){0.f, 0.f, 0.f, 0.f};
        acc[ni][1] = (f32x4){0.f, 0.f, 0.f, 0.f};
    }
    short8 Bb[2][NI][2];
    #pragma unroll
    for (int ni = 0; ni < NI; ++ni) {
        Bb[0][ni][0] = ld8_(bp + (size_t)ni * 128 * KP);
        Bb[0][ni][1] = ld8_(bp + (size_t)ni * 128 * KP + 32);
    }
    #pragma unroll
    for (int ki = 0; ki < KI; ++ki) {
        const int cur = ki & 1, nxt = cur ^ 1;
        if (ki + 1 < KI) {
            #pragma unroll
            for (int ni = 0; ni < NI; ++ni) {
                Bb[nxt][ni][0] = ld8_(bp + (ki + 1) * 64 + (size_t)ni * 128 * KP);
                Bb[nxt][ni][1] = ld8_(bp + (ki + 1) * 64 + (size_t)ni * 128 * KP + 32);
            }
        }
        short8 a[2][2];
        #pragma unroll
        for (int rg = 0; rg < 2; ++rg)
            #pragma unroll
            for (int s = 0; s < 2; ++s)
                a[rg][s] = ld8_(actin + ((rg * KS + ki * 2 + s) * 64 + l) * 8);
        #pragma unroll
        for (int ni = 0; ni < NI; ++ni)
            #pragma unroll
            for (int rg = 0; rg < 2; ++rg) {
                acc[ni][rg] = __builtin_amdgcn_mfma_f32_16x16x32_bf16(a[rg][0], Bb[cur][ni][0], acc[ni][rg], 0, 0, 0);
                acc[ni][rg] = __builtin_amdgcn_mfma_f32_16x16x32_bf16(a[rg][1], Bb[cur][ni][1], acc[ni][rg], 0, 0, 0);
            }
    }

    if constexpr (LMODE == 0) {
        #pragma unroll
        for (int ni = 0; ni < NI; ++ni) {
            const int c = ni * 128 + w * 16 + cl;
            const float bb = (c < HH) ? bL[c] : 0.f;
            #pragma unroll
            for (int rg = 0; rg < 2; ++rg)
                #pragma unroll
                for (int rr = 0; rr < 4; ++rr) {
                    float o = (c < HH) ? elu_(acc[ni][rg][rr] + bb) : 0.f;
                    if (c < 320)
                        actout[((rg * 10 + (c >> 5)) * 64 + (g4 + rr) + (((c >> 3) & 3) << 4)) * 8 + (c & 7)] = bf16_(o);
                }
        }
    } else {
        const int c = w * 16 + cl;
        if (c < 20) {
            #pragma unroll
            for (int rg = 0; rg < 2; ++rg)
                #pragma unroll
                for (int rr = 0; rr < 4; ++rr)
                    c3L[(rg * 16 + g4 + rr) * 24 + c] = acc[0][rg][rr] + bL[c];
        }
    }
}

// ---------------------------------------------------------------------------
// dec3: ni-major, ni-pipelined. B ring = one ni's K-panel (KI x 2 short8),
// prefetched one ni ahead (~20 loads in flight under 20-MFMA chain).
// Per-lane row-sum partials; single cross-lane reduce at end -> redL.
// ---------------------------------------------------------------------------
template<int KP, int KI, int NI>
__device__ __forceinline__ void layerD3(
    const int tid,
    const unsigned short* __restrict__ xs,
    const unsigned short* __restrict__ actin,
    const unsigned short* __restrict__ Wt,
    const float* __restrict__ bL,
    float* __restrict__ redL)
{
    const int w = tid >> 6, l = tid & 63;
    const int cl = l & 15, hi = l >> 4, g4 = hi << 2;
    constexpr int KS = KP / 32;
    const unsigned short* bp = Wt + (size_t)(w * 16 + cl) * KP + hi * 8;

    short8 Bb[2][KI][2];
    #pragma unroll
    for (int ki = 0; ki < KI; ++ki) {
        Bb[0][ki][0] = ld8_(bp + ki * 64);
        Bb[0][ki][1] = ld8_(bp + ki * 64 + 32);
    }
    float rs[2][4] = {{0.f, 0.f, 0.f, 0.f}, {0.f, 0.f, 0.f, 0.f}};

    #pragma unroll
    for (int ni = 0; ni < NI; ++ni) {
        const int cur = ni & 1, nxt = cur ^ 1;
        if (ni + 1 < NI) {
            const unsigned short* bn = bp + (size_t)(ni + 1) * 128 * KP;
            #pragma unroll
            for (int ki = 0; ki < KI; ++ki) {
                Bb[nxt][ki][0] = ld8_(bn + ki * 64);
                Bb[nxt][ki][1] = ld8_(bn + ki * 64 + 32);
            }
        }
        f32x4 acc[2];
        acc[0] = (f32x4){0.f, 0.f, 0.f, 0.f};
        acc[1] = (f32x4){0.f, 0.f, 0.f, 0.f};
        #pragma unroll
        for (int ki = 0; ki < KI; ++ki) {
            short8 a[2][2];
            #pragma unroll
            for (int rg = 0; rg < 2; ++rg)
                #pragma unroll
                for (int s = 0; s < 2; ++s)
                    a[rg][s] = ld8_(actin + ((rg * KS + ki * 2 + s) * 64 + l) * 8);
            #pragma unroll
            for (int rg = 0; rg < 2; ++rg) {
                acc[rg] = __builtin_amdgcn_mfma_f32_16x16x32_bf16(a[rg][0], Bb[cur][ki][0], acc[rg], 0, 0, 0);
                acc[rg] = __builtin_amdgcn_mfma_f32_16x16x32_bf16(a[rg][1], Bb[cur][ki][1], acc[rg], 0, 0, 0);
            }
        }
        const int c = ni * 128 + w * 16 + cl;
        if (c < XD) {
            const float bb = bL[c];
            #pragma unroll
            for (int rg = 0; rg < 2; ++rg)
                #pragma unroll
                for (int rr = 0; rr < 4; ++rr) {
                    float lv = acc[rg][rr] + bb;
                    float xv = b2f_(xs[((rg * 26 + (c >> 5)) * 64 + (g4 + rr) + (((c >> 3) & 3) << 4)) * 8 + (c & 7)]);
                    rs[rg][rr] += xv * lv - sp_(lv);
                }
        }
    }
    #pragma unroll
    for (int rg = 0; rg < 2; ++rg)
        #pragma unroll
        for (int rr = 0; rr < 4; ++rr) {
            float s = rs[rg][rr];
            s += __shfl_xor(s, 1); s += __shfl_xor(s, 2);
            s += __shfl_xor(s, 4); s += __shfl_xor(s, 8);
            if (cl == 0) redL[(rg * 16 + g4 + rr) * 8 + w] = s;
        }
}

// ---------------------------------------------------------------------------
// KI=1 layers (KP=64, A in regs once), ni-pipelined B (one ni ahead).
// LMODE 0: dec1 (elu store per ni). LMODE 3: comp — per-lane online
// logsumexp over ni; one pairwise online merge across 16 lanes at end.
// ---------------------------------------------------------------------------
template<int LMODE, int NI>
__device__ __forceinline__ void layerNM(
    const int tid,
    const unsigned short* __restrict__ actin,
    const unsigned short* __restrict__ Wt,
    const float* __restrict__ bL,
    unsigned short* __restrict__ actout,
    float* __restrict__ redM, float* __restrict__ redS)
{
    const int w = tid >> 6, l = tid & 63;
    const int cl = l & 15, hi = l >> 4, g4 = hi << 2;
    const unsigned short* bp = Wt + (size_t)(w * 16 + cl) * 64 + hi * 8;

    short8 a[2][2];
    #pragma unroll
    for (int rg = 0; rg < 2; ++rg)
        #pragma unroll
        for (int s = 0; s < 2; ++s)
            a[rg][s] = ld8_(actin + ((rg * 2 + s) * 64 + l) * 8);

    float rA[2][4], rB[2][4];
    #pragma unroll
    for (int rg = 0; rg < 2; ++rg)
        #pragma unroll
        for (int rr = 0; rr < 4; ++rr) { rA[rg][rr] = -1e30f; rB[rg][rr] = 0.f; }

    short8 c0 = ld8_(bp), c1 = ld8_(bp + 32);
    #pragma unroll
    for (int ni = 0; ni < NI; ++ni) {
        short8 p0 = c0, p1 = c1;
        if (ni + 1 < NI) {
            p0 = ld8_(bp + (size_t)(ni + 1) * 128 * 64);
            p1 = ld8_(bp + (size_t)(ni + 1) * 128 * 64 + 32);
        }
        f32x4 acc[2];
        #pragma unroll
        for (int rg = 0; rg < 2; ++rg) {
            acc[rg] = __builtin_amdgcn_mfma_f32_16x16x32_bf16(a[rg][0], c0, (f32x4){0.f, 0.f, 0.f, 0.f}, 0, 0, 0);
            acc[rg] = __builtin_amdgcn_mfma_f32_16x16x32_bf16(a[rg][1], c1, acc[rg], 0, 0, 0);
        }
        if constexpr (LMODE == 0) {
            const int c = ni * 128 + w * 16 + cl;
            const float bb = (c < HH) ? bL[c] : 0.f;
            #pragma unroll
            for (int rg = 0; rg < 2; ++rg)
                #pragma unroll
                for (int rr = 0; rr < 4; ++rr) {
                    float o = (c < HH) ? elu_(acc[rg][rr] + bb) : 0.f;
                    if (c < 320)
                        actout[((rg * 10 + (c >> 5)) * 64 + (g4 + rr) + (((c >> 3) & 3) << 4)) * 8 + (c & 7)] = bf16_(o);
                }
        } else {
            #pragma unroll
            for (int rg = 0; rg < 2; ++rg)
                #pragma unroll
                for (int rr = 0; rr < 4; ++rr) {
                    float v = acc[rg][rr];
                    float mx = fmaxf(v, rA[rg][rr]);
                    rB[rg][rr] = rB[rg][rr] * __expf(rA[rg][rr] - mx) + __expf(v - mx);
                    rA[rg][rr] = mx;
                }
        }
        c0 = p0; c1 = p1;
    }
    if constexpr (LMODE == 3) {
        #pragma unroll
        for (int d = 1; d <= 8; d <<= 1)
            #pragma unroll
            for (int rg = 0; rg < 2; ++rg)
                #pragma unroll
                for (int rr = 0; rr < 4; ++rr) {
                    float mo = __shfl_xor(rA[rg][rr], d);
                    float so = __shfl_xor(rB[rg][rr], d);
                    float M = fmaxf(rA[rg][rr], mo);
                    rB[rg][rr] = rB[rg][rr] * __expf(rA[rg][rr] - M) + so * __expf(mo - M);
                    rA[rg][rr] = M;
                }
        if (cl == 0) {
            #pragma unroll
            for (int rg = 0; rg < 2; ++rg)
                #pragma unroll
                for (int rr = 0; rr < 4; ++rr) {
                    redM[(rg * 16 + g4 + rr) * 8 + w] = rA[rg][rr];
                    redS[(rg * 16 + g4 + rr) * 8 + w] = rB[rg][rr];
                }
        }
    }
}

__global__ __launch_bounds__(512, 2)
void fused_k(const float* __restrict__ xg,
             const unsigned short* __restrict__ w1t, const float* __restrict__ eb1,
             const unsigned short* __restrict__ w2t, const float* __restrict__ eb2,
             const unsigned short* __restrict__ w3t, const float* __restrict__ eb3,
             const unsigned short* __restrict__ d1t, const float* __restrict__ db1,
             const unsigned short* __restrict__ d2t, const float* __restrict__ db2,
             const unsigned short* __restrict__ d3t, const float* __restrict__ db3,
             const unsigned short* __restrict__ G,
             const float* __restrict__ eps, float* __restrict__ part)
{
    __shared__ __align__(16) unsigned short xs[26624];    // 32x832 bf16, frag-major
    __shared__ __align__(16) unsigned short actP[10240];  // 32x320
    __shared__ __align__(16) unsigned short actQ[10240];
    __shared__ __align__(16) unsigned short fbL[2048];    // 32x64
    __shared__ float biasAll[2112];  // eb1@0 eb2@320 eb3@640 db1@672 db2@992 db3@1312
    __shared__ float c3L[768];
    __shared__ float redM[256], redS[256], redL[256], lqzL[32];

    const int tid = threadIdx.x;
    const int m0 = blockIdx.x * 32;

    // stage x (fp32 -> bf16, fragment-major), zero fb FULLY, preload ALL biases
    #pragma unroll
    for (int it = 0; it < 7; ++it) {
        const int c = tid + it * 512;
        if (c < 32 * 104) {
            const int row = c / 104, kc = c - row * 104;
            const int k0 = kc * 8;
            short8 v8 = (short8){0, 0, 0, 0, 0, 0, 0, 0};
            if (k0 < XD) {
                const float* src = xg + (size_t)(m0 + row) * XD + k0;
                float4 f0 = *reinterpret_cast<const float4*>(src);
                float4 f1 = *reinterpret_cast<const float4*>(src + 4);
                v8[0] = (short)bf16_(f0.x); v8[1] = (short)bf16_(f0.y);
                v8[2] = (short)bf16_(f0.z); v8[3] = (short)bf16_(f0.w);
                v8[4] = (short)bf16_(f1.x); v8[5] = (short)bf16_(f1.y);
                v8[6] = (short)bf16_(f1.z); v8[7] = (short)bf16_(f1.w);
            }
            const int rg = row >> 4;
            const int lane = (row & 15) + ((kc & 3) << 4);
            *reinterpret_cast<short8*>(&xs[((rg * 26 + (kc >> 2)) * 64 + lane) * 8]) = v8;
        }
    }
    if (tid < 256) reinterpret_cast<uint4*>(fbL)[tid] = (uint4){0u, 0u, 0u, 0u};  // ALL 4096B
    if (tid < HH) biasAll[tid] = eb1[tid];
    if (tid < HH) biasAll[320 + tid] = eb2[tid];
    if (tid < 20) biasAll[640 + tid] = eb3[tid];
    if (tid < HH) biasAll[672 + tid] = db1[tid];
    if (tid < HH) biasAll[992 + tid] = db2[tid];
    for (int i = tid; i < XD; i += 512) biasAll[1312 + i] = db3[i];
    __syncthreads();

    layerKM<0, 832, 13, 3>(tid, xs, w1t, biasAll, actP, nullptr);
    __syncthreads();
    layerKM<0, 320, 5, 3>(tid, actP, w2t, biasAll + 320, actQ, nullptr);
    __syncthreads();
    layerKM<1, 320, 5, 1>(tid, actQ, w3t, biasAll + 640, nullptr, c3L);
    __syncthreads();

    if (tid < 32) {
        float a = 0.f;
        #pragma unroll
        for (int j = 0; j < ZD; ++j) {
            float qm = c3L[tid * 24 + j];
            float qh = c3L[tid * 24 + 10 + j];
            float qv = sp_(qh) + 1e-8f;
            float e  = eps[(size_t)(m0 + tid) * ZD + j];
            float zj = qm + sqrtf(qv) * e;
            fbw(fbL, tid, j,      bf16_(zj * zj));
            fbw(fbL, tid, 10 + j, bf16_(zj));
            float d = zj - qm;
            a += __logf(6.283185307179586f * qv) + d * d / qv;
        }
        fbw(fbL, tid, 20, bf16_(1.f));   // picks up c_k hi/lo from G cols 20/21
        fbw(fbL, tid, 21, bf16_(1.f));
        lqzL[tid] = -0.5f * a;
    }
    __syncthreads();

    layerNM<0, 3>(tid, fbL, d1t, biasAll + 672, actP, nullptr, nullptr);
    __syncthreads();
    layerKM<0, 320, 5, 3>(tid, actP, d2t, biasAll + 992, actQ, nullptr);
    __syncthreads();
    layerD3<320, 5, 7>(tid, xs, actQ, d3t, biasAll + 1312, redL);
    __syncthreads();
    layerNM<3, 16>(tid, fbL, G, nullptr, nullptr, redM, redS);
    __syncthreads();

    if (tid < 32) {
        float M = -1e30f;
        #pragma unroll
        for (int w8 = 0; w8 < 8; ++w8) M = fmaxf(M, redM[tid * 8 + w8]);
        float S = 0.f;
        #pragma unroll
        for (int w8 = 0; w8 < 8; ++w8) S += redS[tid * 8 + w8] * __expf(redM[tid * 8 + w8] - M);
        float lpz = M + __logf(S) - 7.6009024595420824f;  // log(2000)
        float lpx = 0.f;
        #pragma unroll
        for (int w8 = 0; w8 < 8; ++w8) lpx += redL[tid * 8 + w8];
        float kl = lqzL[tid] - lpz;
        float ne = kl - lpx, re = -lpx;
        #pragma unroll
        for (int d = 1; d <= 16; d <<= 1) {
            ne += __shfl_xor(ne, d); kl += __shfl_xor(kl, d); re += __shfl_xor(re, d);
        }
        if (tid == 0) {
            part[blockIdx.x * 3 + 0] = ne;
            part[blockIdx.x * 3 + 1] = kl;
            part[blockIdx.x * 3 + 2] = re;
        }
    }
}

// weight transposes/pads + GMM coef matrix (c_k folded as bf16 hi/lo cols)
__global__ __launch_bounds__(256)
void prep_k(const float* __restrict__ ew1, const float* __restrict__ ew2,
            const float* __restrict__ ew3, const float* __restrict__ dw1,
            const float* __restrict__ dw2, const float* __restrict__ dw3,
            const float* __restrict__ zpre,
            unsigned short* __restrict__ w1t, unsigned short* __restrict__ w2t,
            unsigned short* __restrict__ w3t, unsigned short* __restrict__ d1t,
            unsigned short* __restrict__ d2t, unsigned short* __restrict__ d3t,
            unsigned short* __restrict__ G)
{
    const int idx = blockIdx.x * 256 + threadIdx.x;
    const int y = blockIdx.y;
    if (y == 0) {
        if (idx >= 384 * 832) return;
        int n = idx / 832, k = idx - n * 832;
        w1t[idx] = bf16_((n < HH && k < XD) ? ew1[(size_t)k * HH + n] : 0.f);
    } else if (y == 1) {
        if (idx >= 384 * 320) return;
        int n = idx / 320, k = idx - n * 320;
        w2t[idx] = bf16_((n < HH && k < HH) ? ew2[(size_t)k * HH + n] : 0.f);
    } else if (y == 2) {
        if (idx >= 128 * 320) return;
        int n = idx / 320, k = idx - n * 320;
        w3t[idx] = bf16_((n < 2 * ZD && k < HH) ? ew3[(size_t)k * 2 * ZD + n] : 0.f);
    } else if (y == 3) {   // d1t [384][64]; dw1 rows at k=10..19 (fb layout: z at 10..19)
        if (idx >= 384 * 64) return;
        int n = idx / 64, k = idx - n * 64;
        float v = (n < HH && k >= 10 && k < 20) ? dw1[(size_t)(k - 10) * HH + n] : 0.f;
        d1t[idx] = bf16_(v);
    } else if (y == 4) {
        if (idx >= 384 * 320) return;
        int n = idx / 320, k = idx - n * 320;
        d2t[idx] = bf16_((n < HH && k < HH) ? dw2[(size_t)k * HH + n] : 0.f);
    } else if (y == 5) {
        if (idx >= 896 * 320) return;
        int n = idx / 320, k = idx - n * 320;
        d3t[idx] = bf16_((n < XD && k < HH) ? dw3[(size_t)k * XD + n] : 0.f);
    } else {
        if (idx >= 2048) return;
        int k = idx;
        if (k < KK) {
            float csum = 0.f;
            #pragma unroll
            for (int j = 0; j < ZD; ++j) {
                float m = zpre[k * ZD + j];
                float h = zpre[(KK + k) * ZD + j];
                float v = sp_(h) + 1e-8f;
                G[k * 64 + j] = bf16_(-0.5f / v);
                G[k * 64 + 10 + j] = bf16_(m / v);
                csum += __logf(6.283185307179586f * v) + m * m / v;
            }
            float ck = -0.5f * csum;
            unsigned short hic = bf16_(ck);
            G[k * 64 + 20] = hic;
            G[k * 64 + 21] = bf16_(ck - b2f_(hic));
            #pragma unroll
            for (int j = 22; j < 64; ++j) G[k * 64 + j] = 0;
        } else {
            #pragma unroll
            for (int j = 0; j < 20; ++j) G[k * 64 + j] = 0;
            G[k * 64 + 20] = bf16_(-1e30f);
            G[k * 64 + 21] = 0;
            #pragma unroll
            for (int j = 22; j < 64; ++j) G[k * 64 + j] = 0;
        }
    }
}

__global__ void fin_k(const float* __restrict__ part, float* __restrict__ out)
{
    int c = threadIdx.x >> 6, l = threadIdx.x & 63;
    if (c < 3) {
        float s = 0.f;
        for (int i = l; i < 256; i += 64) s += part[i * 3 + c];
        #pragma unroll
        for (int d = 1; d < 64; d <<= 1) s += __shfl_xor(s, d);
        if (l == 0) out[c] = s / (float)BB;
    }
}

extern "C" void kernel_launch(void* const* d_in, const int* in_sizes, int n_in,
                              void* d_out, int out_size, void* d_ws, size_t ws_size,
                              hipStream_t stream)
{
    const float* x    = (const float*)d_in[0];
    const float* eps  = (const float*)d_in[1];
    const float* zpre = (const float*)d_in[2];
    const float* ew1  = (const float*)d_in[3];
    const float* eb1  = (const float*)d_in[4];
    const float* ew2  = (const float*)d_in[5];
    const float* eb2  = (const float*)d_in[6];
    const float* ew3  = (const float*)d_in[7];
    const float* eb3  = (const float*)d_in[8];
    const float* dw1  = (const float*)d_in[9];
    const float* db1  = (const float*)d_in[10];
    const float* dw2  = (const float*)d_in[11];
    const float* db2  = (const float*)d_in[12];
    const float* dw3  = (const float*)d_in[13];
    const float* db3  = (const float*)d_in[14];
    float* out = (float*)d_out;

    float* ws   = (float*)d_ws;
    float* part = ws;                        // 256*3
    unsigned short* ub = (unsigned short*)(part + 768);
    unsigned short* w1t = ub; ub += 384 * 832;
    unsigned short* w2t = ub; ub += 384 * 320;
    unsigned short* w3t = ub; ub += 128 * 320;
    unsigned short* d1t = ub; ub += 384 * 64;
    unsigned short* d2t = ub; ub += 384 * 320;
    unsigned short* d3t = ub; ub += 896 * 320;
    unsigned short* G   = ub; ub += 2048 * 64;

    dim3 blk(256);
    prep_k<<<dim3(1248, 7), blk, 0, stream>>>(ew1, ew2, ew3, dw1, dw2, dw3, zpre,
                                              w1t, w2t, w3t, d1t, d2t, d3t, G);
    fused_k<<<256, 512, 0, stream>>>(x, w1t, eb1, w2t, eb2, w3t, eb3,
                                     d1t, db1, d2t, db2, d3t, db3, G, eps, part);
    fin_k<<<1, 256, 0, stream>>>(part, out);
}